// Round 3
// baseline (153.883 us; speedup 1.0000x reference)
//
#include <hip/hip_runtime.h>
#include <math.h>

typedef unsigned short u16;
typedef unsigned int u32;
typedef __attribute__((ext_vector_type(8))) short bf16x8;
typedef __attribute__((ext_vector_type(4))) float f32x4;

#define AS1 __attribute__((address_space(1)))
#define AS3 __attribute__((address_space(3)))

#if __has_builtin(__builtin_amdgcn_exp2f)
#define EXP2F __builtin_amdgcn_exp2f
#else
#define EXP2F exp2f
#endif

__device__ __forceinline__ float sigf(float x){ return 1.f/(1.f+__expf(-x)); }
__device__ __forceinline__ float geluf(float x){
  float x3 = x*x*x;
  return 0.5f*x*(1.f + tanhf(0.7978845608f*(x + 0.044715f*x3)));
}
__device__ __forceinline__ float bf2f(u16 u){ return __uint_as_float(((u32)u)<<16); }
__device__ __forceinline__ u16 f2bf(float x){           // round-to-nearest-even
  u32 u = __float_as_uint(x);
  u32 r = (u + 0x7FFFu + ((u>>16)&1u)) >> 16;
  return (u16)r;
}

// ---------------------------------------------------------------------------
// bf16 MFMA GEMM: C[m][n] = sum_k A[m][k] * W[n][k]  (both K-contiguous)
// 128x128 tile, BK=64, 4 waves (2x2), each wave 64x64 = 4x4 fragments of 16x16.
// global_load_lds(16B) staging with XOR-swizzled source <-> swizzled ds_read.
// EPI: 0=store f32, 1=+bias f32, 2=gelu(+bias)->bf16, 5=bf16,
//      3=x0+g_m*acc f32, 4=x1+g_p*(acc+bias) -> inverse pixel-shuffle scatter,
//      6=combined x_proj: n<512 -> softplus(acc+dt_bias) f32 delta,
//        n>=512 -> BC f32 (8192x32).
// ---------------------------------------------------------------------------
template<int EPI>
__global__ __launch_bounds__(256) void gemm_mfma(
    const u16* __restrict__ A, int lda,
    const u16* __restrict__ W, int ldw,
    int K, int Nvalid,
    const float* __restrict__ bias,
    void* __restrict__ Cout, int ldc,
    const float* __restrict__ aux0,   // x0 (EPI3) / x1 (EPI4), ld 256, fp32
    const float* __restrict__ mods,   // (512,1536) fp32
    float* __restrict__ out4)         // final output (EPI4) / BC (EPI6)
{
  __shared__ u16 Alds[128*64];
  __shared__ u16 Blds[128*64];
  const int tid  = threadIdx.x;
  const int lane = tid & 63, wid = tid >> 6;
  const int wr = wid >> 1, wc = wid & 1;
  const int m0 = blockIdx.y*128, n0 = blockIdx.x*128;
  const int ln8 = lane >> 3, lk = lane & 7;

  f32x4 acc[4][4];
#pragma unroll
  for (int i=0;i<4;i++)
#pragma unroll
    for (int j=0;j<4;j++) acc[i][j] = (f32x4){0.f,0.f,0.f,0.f};

  for (int k0 = 0; k0 < K; k0 += 64){
#pragma unroll
    for (int j = 0; j < 4; j++){
      const int c   = wid + j*4;          // chunk 0..15, 1KB each (8 rows)
      const int row = c*8 + ln8;
      const int ks  = lk ^ (row & 7);     // inverse-swizzled source k-slot
      {
        const u16* src = A + (size_t)(m0+row)*lda + k0 + 8*ks;
        __builtin_amdgcn_global_load_lds((AS1 const void*)src,
                                         (AS3 void*)&Alds[c*512], 16, 0, 0);
      }
      {
        int rn = n0 + row; if (rn > Nvalid-1) rn = Nvalid-1;
        const u16* src = W + (size_t)rn*ldw + k0 + 8*ks;
        __builtin_amdgcn_global_load_lds((AS1 const void*)src,
                                         (AS3 void*)&Blds[c*512], 16, 0, 0);
      }
    }
    __syncthreads();
#pragma unroll
    for (int kk = 0; kk < 2; kk++){
      bf16x8 af[4], bf[4];
#pragma unroll
      for (int i = 0; i < 4; i++){
        const int row = wr*64 + i*16 + (lane & 15);
        const int col = wc*64 + i*16 + (lane & 15);
        const int ks  = kk*4 + (lane >> 4);
        af[i] = *(const bf16x8*)&Alds[row*64 + 8*(ks ^ (row & 7))];
        bf[i] = *(const bf16x8*)&Blds[col*64 + 8*(ks ^ (col & 7))];
      }
#pragma unroll
      for (int i = 0; i < 4; i++)
#pragma unroll
        for (int j = 0; j < 4; j++)
          acc[i][j] = __builtin_amdgcn_mfma_f32_16x16x32_bf16(af[i], bf[j], acc[i][j], 0, 0, 0);
    }
    __syncthreads();
  }

  // Epilogue. C/D layout: col = lane&15, row = (lane>>4)*4 + r.
#pragma unroll
  for (int j = 0; j < 4; j++){
    const int n = n0 + wc*64 + j*16 + (lane & 15);
    if (n >= Nvalid) continue;
    float bv = 0.f;
    if constexpr (EPI==1 || EPI==2 || EPI==4) bv = bias[n];
    if constexpr (EPI==6){ if (n < 512) bv = bias[n]; }
#pragma unroll
    for (int i = 0; i < 4; i++){
#pragma unroll
      for (int r = 0; r < 4; r++){
        const int m = m0 + wr*64 + i*16 + (lane>>4)*4 + r;
        const int b = m >> 4;
        float x = acc[i][j][r];
        if constexpr (EPI==0){ ((float*)Cout)[(size_t)m*ldc+n] = x; }
        if constexpr (EPI==1){ ((float*)Cout)[(size_t)m*ldc+n] = x + bv; }
        if constexpr (EPI==2){ ((u16*)Cout)[(size_t)m*ldc+n] = f2bf(geluf(x + bv)); }
        if constexpr (EPI==5){ ((u16*)Cout)[(size_t)m*ldc+n] = f2bf(x); }
        if constexpr (EPI==3){
          ((float*)Cout)[(size_t)m*ldc+n] =
              aux0[(size_t)m*256+n] + mods[(size_t)b*1536+512+n]*x;
        }
        if constexpr (EPI==4){
          float v = aux0[(size_t)m*256+n] + mods[(size_t)b*1536+1280+n]*(x + bv);
          const int pos = m & 15;
          const int c = n>>6, hr=(n>>3)&7, wrr=n&7;
          const int hh = (pos>>2)*8+hr, ww=(pos&3)*8+wrr;
          out4[(((size_t)b*4+c)*32+hh)*32+ww] = v;
        }
        if constexpr (EPI==6){
          if (n < 512){
            float dt = x + bv;
            float del = (dt > 20.f) ? dt : log1pf(__expf(dt));
            ((float*)Cout)[(size_t)m*512+n] = del;
          } else {
            out4[(size_t)m*32 + (n-512)] = x;
          }
        }
      }
    }
  }
}

// fp32 -> bf16 conversion of F_clip + 6 weight matrices, one fused kernel.
__global__ __launch_bounds__(256) void cvt_bf16(
    const float* __restrict__ clip, const float* __restrict__ fsw,
    const float* __restrict__ inp,  const float* __restrict__ xp,
    const float* __restrict__ outp, const float* __restrict__ f1,
    const float* __restrict__ f2,   u16* __restrict__ dst)
{
  const int q = blockIdx.x*256 + threadIdx.x;   // quad index (x4 elems)
  const float* s; int off;
  if      (q < 65536)  { s = clip; off = q*4; }
  else if (q < 262144) { s = fsw;  off = (q-65536)*4; }
  else if (q < 327680) { s = inp;  off = (q-262144)*4; }
  else if (q < 333824) { s = xp;   off = (q-327680)*4; }
  else if (q < 366592) { s = outp; off = (q-333824)*4; }
  else if (q < 382976) { s = f1;   off = (q-366592)*4; }
  else                 { s = f2;   off = (q-382976)*4; }
  float4 v = *(const float4*)&s[off];
  uint2 o;
  o.x = (u32)f2bf(v.x) | ((u32)f2bf(v.y)<<16);
  o.y = (u32)f2bf(v.z) | ((u32)f2bf(v.w)<<16);
  *(uint2*)&dst[(size_t)q*4] = o;
}

// Build combined x_proj weight (544 x 512) in bf16:
// rows 0..511  : Wc = dt_proj_w @ x_proj_w[:16]   (dt path folded into GEMM)
// rows 512..543: x_proj_w rows 16..47 (B and C rows)
__global__ __launch_bounds__(512) void wcomb(
    const float* __restrict__ dtw, const float* __restrict__ xpw,
    u16* __restrict__ wall)
{
  const int n = blockIdx.x;      // 0..543
  const int k = threadIdx.x;     // 0..511
  float v;
  if (n < 512){
    v = 0.f;
#pragma unroll
    for (int r=0;r<16;r++) v = fmaf(dtw[n*16+r], xpw[r*512+k], v);
  } else {
    v = xpw[(size_t)(16 + n-512)*512 + k];
  }
  wall[(size_t)n*512+k] = f2bf(v);
}

// LayerNorm + modulate. SHUF: gather via pixel shuffle, also write x0 (fp32).
template<bool SHUF>
__global__ __launch_bounds__(256) void ln_mod(
    const float* __restrict__ src, const float* __restrict__ mods,
    int sh_off, float* __restrict__ x0_out, u16* __restrict__ u_out)
{
  const int wave = threadIdx.x>>6, lane = threadIdx.x&63;
  const int m = blockIdx.x*4 + wave;
  const int b = m>>4;
  const int c0 = lane*4;
  float4 v;
  if constexpr (SHUF){
    const int pos=m&15, hb=pos>>2, wb=pos&3;
    const int c=c0>>6, hr=(c0>>3)&7, wrb=c0&7;
    v = *(const float4*)&src[(((size_t)b*4+c)*32 + hb*8+hr)*32 + wb*8 + wrb];
  } else {
    v = *(const float4*)&src[(size_t)m*256 + c0];
  }
  float s  = v.x+v.y+v.z+v.w;
  float s2 = v.x*v.x+v.y*v.y+v.z*v.z+v.w*v.w;
#pragma unroll
  for (int off=1; off<64; off<<=1){
    s  += __shfl_xor(s, off);
    s2 += __shfl_xor(s2, off);
  }
  const float mean = s*(1.f/256.f);
  const float var  = s2*(1.f/256.f) - mean*mean;
  const float rs   = rsqrtf(var + 1e-6f);
  float4 sh = *(const float4*)&mods[(size_t)b*1536 + sh_off + c0];
  float4 sc = *(const float4*)&mods[(size_t)b*1536 + sh_off + 256 + c0];
  float ux = (v.x-mean)*rs*(1.f+sc.x) + sh.x;
  float uy = (v.y-mean)*rs*(1.f+sc.y) + sh.y;
  float uz = (v.z-mean)*rs*(1.f+sc.z) + sh.z;
  float uw = (v.w-mean)*rs*(1.f+sc.w) + sh.w;
  if constexpr (SHUF) *(float4*)&x0_out[(size_t)m*256+c0] = v;
  uint2 o;
  o.x = (u32)f2bf(ux) | ((u32)f2bf(uy)<<16);
  o.y = (u32)f2bf(uz) | ((u32)f2bf(uw)<<16);
  *(uint2*)&u_out[(size_t)m*256+c0] = o;
}

// Depthwise causal conv (k=4) + SiLU, bf16 in (x-half of xz) / bf16 out.
__global__ __launch_bounds__(256) void conv_silu(
    const u16* __restrict__ xz, const float* __restrict__ cw,
    const float* __restrict__ cb, u16* __restrict__ xs)
{
  const int t = blockIdx.x*256 + threadIdx.x;
  const int b = t>>9, d = t&511;
  const u16* xp = xz + (size_t)b*16384 + d;
  float x[16];
#pragma unroll
  for (int l=0;l<16;l++) x[l] = bf2f(xp[(size_t)l*1024]);
  const float w0=cw[d*4+0], w1=cw[d*4+1], w2=cw[d*4+2], w3=cw[d*4+3];
  const float bias = cb[d];
  u16* op = xs + (size_t)b*8192 + d;
#pragma unroll
  for (int l=0;l<16;l++){
    float a = bias + w3*x[l];
    if (l>=1) a += w2*x[l-1];
    if (l>=2) a += w1*x[l-2];
    if (l>=3) a += w0*x[l-3];
    a = a*sigf(a);
    op[(size_t)l*512] = f2bf(a);
  }
}

// Selective scan v2. Block per batch (512 threads = channels).
// delta precomputed (softplus done in GEMM epilogue); B/C read via scalar
// loads (block-uniform address); dA via single v_exp (exp2, pre-scaled A).
// y overwrites the x-half of xz (dead after conv), gated by silu(z).
__global__ __launch_bounds__(512) void scan_kernel(
    const u16* __restrict__ xs, u16* __restrict__ xz,
    const float* __restrict__ delta, const float* __restrict__ BC,
    const float* __restrict__ A_log, const float* __restrict__ Dskip)
{
  const int b = blockIdx.x, d = threadIdx.x;
  float An2[16], h[16];
#pragma unroll
  for (int n=0;n<16;n++){
    An2[n] = -__expf(A_log[d*16+n]) * 1.44269504f;   // A * log2(e)
    h[n] = 0.f;
  }
  const float Dv = Dskip[d];
  const float* dp  = delta + (size_t)b*8192 + d;
  const float* bcp = BC + (size_t)b*512;            // (16,32) per batch, uniform
  const u16* xsp = xs + (size_t)b*8192 + d;
  u16* zp = xz + (size_t)b*16384 + d;               // x @ +l*1024, z @ +512
#pragma unroll
  for (int l=0;l<16;l++){
    const float dl = dp[(size_t)l*512];
    const float xl = bf2f(xsp[(size_t)l*512]);
    const float dx = dl*xl;
    float yv = Dv*xl;
#pragma unroll
    for (int n=0;n<16;n++){
      const float dA = EXP2F(dl*An2[n]);
      h[n] = fmaf(dA, h[n], bcp[l*32+n]*dx);
      yv = fmaf(h[n], bcp[l*32+16+n], yv);
    }
    const float zl = bf2f(zp[(size_t)l*1024 + 512]);
    yv *= zl*sigf(zl);
    zp[(size_t)l*1024] = f2bf(yv);
  }
}

extern "C" void kernel_launch(void* const* d_in, const int* in_sizes, int n_in,
                              void* d_out, int out_size, void* d_ws, size_t ws_size,
                              hipStream_t stream)
{
  const float* F_clip    = (const float*)d_in[0];
  const float* F_content = (const float*)d_in[1];
  const float* fs_b      = (const float*)d_in[3];
  const float* conv_w    = (const float*)d_in[5];
  const float* conv_b    = (const float*)d_in[6];
  const float* x_proj_w  = (const float*)d_in[7];
  const float* dt_proj_w = (const float*)d_in[8];
  const float* dt_proj_b = (const float*)d_in[9];
  const float* A_log     = (const float*)d_in[10];
  const float* D_skip    = (const float*)d_in[11];
  const float* fc1_b     = (const float*)d_in[14];
  const float* fc2_b     = (const float*)d_in[16];
  float* out = (float*)d_out;

  float* ws = (float*)d_ws;
  float* w_mods  = ws;                     // 786432 f
  float* w_x0    = w_mods + 786432;        // 2097152 f
  float* w_x1    = w_x0   + 2097152;       // 2097152 f
  float* w_delta = w_x1   + 2097152;       // 4194304 f  (8192 x 512)
  float* w_bc    = w_delta+ 4194304;       // 262144 f   (8192 x 32)
  u16* u_bf    = (u16*)(w_bc + 262144);    // 2097152 h
  u16* xz_bf   = u_bf    + 2097152;        // 8388608 h
  u16* xs_bf   = xz_bf   + 8388608;        // 4194304 h
  u16* u2_bf   = xs_bf   + 4194304;        // 2097152 h
  u16* hmid_bf = u2_bf   + 2097152;        // 2097152 h
  u16* wall_bf = hmid_bf + 2097152;        // 278528 h   (544 x 512)
  u16* wt_bf   = wall_bf + 278528;         // 1597440 h  => total ~79.3 MB

  u16* clip_bf = wt_bf;
  u16* fsw_bf  = wt_bf + 262144;
  u16* inp_bf  = wt_bf + 1048576;
  u16* outp_bf = wt_bf + 1335296;
  u16* fc1_bf  = wt_bf + 1466368;
  u16* fc2_bf  = wt_bf + 1531904;

  // K0: fp32 -> bf16 for F_clip + all GEMM weights
  cvt_bf16<<<1560,256,0,stream>>>(F_clip, (const float*)d_in[2],
      (const float*)d_in[4], (const float*)d_in[7], (const float*)d_in[12],
      (const float*)d_in[13], (const float*)d_in[15], wt_bf);
  // K0b: combined x_proj/dt_proj weight (544 x 512)
  wcomb<<<544,512,0,stream>>>(dt_proj_w, x_proj_w, wall_bf);
  // K1: mods = F_clip @ fs_w.T + fs_b           (512 x 1536, K=512)
  gemm_mfma<1><<<dim3(12,4),256,0,stream>>>(clip_bf,512, fsw_bf,512, 512,1536,
      fs_b, w_mods,1536, nullptr,nullptr,nullptr);
  // K2: pixel shuffle + LN + modulate -> x0 (f32), u (bf16)
  ln_mod<true><<<2048,256,0,stream>>>(F_content, w_mods, 0, w_x0, u_bf);
  // K3: xz = u @ in_proj.T                      (8192 x 1024, K=256) -> bf16
  gemm_mfma<5><<<dim3(8,64),256,0,stream>>>(u_bf,256, inp_bf,256, 256,1024,
      nullptr, xz_bf,1024, nullptr,nullptr,nullptr);
  // K4: depthwise causal conv + silu -> xs (bf16)
  conv_silu<<<1024,256,0,stream>>>(xz_bf, conv_w, conv_b, xs_bf);
  // K4b: [delta | BC] = xs @ Wall.T             (8192 x 544, K=512)
  gemm_mfma<6><<<dim3(5,64),256,0,stream>>>(xs_bf,512, wall_bf,512, 512,544,
      dt_proj_b, w_delta,512, nullptr,nullptr, w_bc);
  // K5: selective scan + gate -> y (bf16, into xz x-half)
  scan_kernel<<<512,512,0,stream>>>(xs_bf, xz_bf, w_delta, w_bc, A_log, D_skip);
  // K6: x1 = x0 + g_m * (y @ out_proj.T)        (8192 x 256, K=512) -> f32
  gemm_mfma<3><<<dim3(2,64),256,0,stream>>>(xz_bf,1024, outp_bf,512, 512,256,
      nullptr, w_x1,256, w_x0, w_mods, nullptr);
  // K6b: LN + modulate -> u2 (bf16)
  ln_mod<false><<<2048,256,0,stream>>>(w_x1, w_mods, 768, nullptr, u2_bf);
  // K7: hmid = gelu(u2 @ fc1.T + b)             (8192 x 256, K=256) -> bf16
  gemm_mfma<2><<<dim3(2,64),256,0,stream>>>(u2_bf,256, fc1_bf,256, 256,256,
      fc1_b, hmid_bf,256, nullptr,nullptr,nullptr);
  // K8: out = unshuffle(x1 + g_p*(hmid @ fc2.T + b))
  gemm_mfma<4><<<dim3(2,64),256,0,stream>>>(hmid_bf,256, fc2_bf,256, 256,256,
      fc2_b, nullptr,256, w_x1, w_mods, out);
}

// Round 4
// 125.055 us; speedup vs baseline: 1.2305x; 1.2305x over previous
//
#include <hip/hip_runtime.h>
#include <math.h>

typedef unsigned short u16;
typedef unsigned int u32;
typedef __attribute__((ext_vector_type(8))) short bf16x8;
typedef __attribute__((ext_vector_type(4))) float f32x4;

#define AS1 __attribute__((address_space(1)))
#define AS3 __attribute__((address_space(3)))

#if __has_builtin(__builtin_amdgcn_exp2f)
#define EXP2F __builtin_amdgcn_exp2f
#else
#define EXP2F exp2f
#endif

__device__ __forceinline__ float sigf(float x){ return 1.f/(1.f+__expf(-x)); }
__device__ __forceinline__ float geluf(float x){
  float x3 = x*x*x;
  return 0.5f*x*(1.f + tanhf(0.7978845608f*(x + 0.044715f*x3)));
}
__device__ __forceinline__ float bf2f(u16 u){ return __uint_as_float(((u32)u)<<16); }
__device__ __forceinline__ u16 f2bf(float x){           // round-to-nearest-even
  u32 u = __float_as_uint(x);
  u32 r = (u + 0x7FFFu + ((u>>16)&1u)) >> 16;
  return (u16)r;
}

// ---------------------------------------------------------------------------
// bf16 MFMA GEMM: C[m][n] = sum_k A[m][k] * W[n][k]  (both K-contiguous)
// 64x64 tile, BK=64, 4 waves (2x2), each wave 32x32 = 2x2 fragments of 16x16.
// Small tile -> big grids (2-8 blocks/CU) so inter-block overlap hides the
// per-K-step vmcnt(0) barrier drain (round-3 128^2 tiles ran at 1 block/CU,
// OccupancyPercent 9%, MfmaUtil 4%).
// global_load_lds(16B) staging, XOR-swizzled source <-> swizzled ds_read.
// EPI: 0=store f32, 1=+bias f32, 2=gelu(+bias)->bf16, 5=bf16,
//      3=x0+g_m*acc f32, 4=x1+g_p*(acc+bias) -> inverse pixel-shuffle scatter,
//      6=combined x_proj: n<512 -> softplus(acc+dt_bias) f32 delta,
//        n>=512 -> BC f32 (8192x32).
// ---------------------------------------------------------------------------
template<int EPI>
__global__ __launch_bounds__(256) void gemm_mfma(
    const u16* __restrict__ A, int lda,
    const u16* __restrict__ W, int ldw,
    int K, int Nvalid,
    const float* __restrict__ bias,
    void* __restrict__ Cout, int ldc,
    const float* __restrict__ aux0,   // x0 (EPI3) / x1 (EPI4), ld 256, fp32
    const float* __restrict__ mods,   // (512,1536) fp32
    float* __restrict__ out4)         // final output (EPI4) / BC (EPI6)
{
  __shared__ u16 Alds[64*64];
  __shared__ u16 Blds[64*64];
  const int tid  = threadIdx.x;
  const int lane = tid & 63, wid = tid >> 6;
  const int wr = wid >> 1, wc = wid & 1;
  const int m0 = blockIdx.y*64, n0 = blockIdx.x*64;
  const int ln8 = lane >> 3, lk = lane & 7;

  f32x4 acc[2][2];
#pragma unroll
  for (int i=0;i<2;i++)
#pragma unroll
    for (int j=0;j<2;j++) acc[i][j] = (f32x4){0.f,0.f,0.f,0.f};

  for (int k0 = 0; k0 < K; k0 += 64){
#pragma unroll
    for (int j = 0; j < 2; j++){
      const int c   = j*4 + wid;          // chunk 0..7, 1KB each (8 rows)
      const int row = c*8 + ln8;          // 0..63
      const int ks  = lk ^ (row & 7);     // inverse-swizzled source k-slot
      {
        const u16* src = A + (size_t)(m0+row)*lda + k0 + 8*ks;
        __builtin_amdgcn_global_load_lds((AS1 const void*)src,
                                         (AS3 void*)&Alds[c*512], 16, 0, 0);
      }
      {
        int rn = n0 + row; if (rn > Nvalid-1) rn = Nvalid-1;
        const u16* src = W + (size_t)rn*ldw + k0 + 8*ks;
        __builtin_amdgcn_global_load_lds((AS1 const void*)src,
                                         (AS3 void*)&Blds[c*512], 16, 0, 0);
      }
    }
    __syncthreads();
#pragma unroll
    for (int kk = 0; kk < 2; kk++){
      bf16x8 af[2], bfr[2];
#pragma unroll
      for (int i = 0; i < 2; i++){
        const int row = wr*32 + i*16 + (lane & 15);
        const int col = wc*32 + i*16 + (lane & 15);
        const int ks  = kk*4 + (lane >> 4);
        af[i]  = *(const bf16x8*)&Alds[row*64 + 8*(ks ^ (row & 7))];
        bfr[i] = *(const bf16x8*)&Blds[col*64 + 8*(ks ^ (col & 7))];
      }
#pragma unroll
      for (int i = 0; i < 2; i++)
#pragma unroll
        for (int j = 0; j < 2; j++)
          acc[i][j] = __builtin_amdgcn_mfma_f32_16x16x32_bf16(af[i], bfr[j], acc[i][j], 0, 0, 0);
    }
    __syncthreads();
  }

  // Epilogue. C/D layout: col = lane&15, row = (lane>>4)*4 + r.
#pragma unroll
  for (int j = 0; j < 2; j++){
    const int n = n0 + wc*32 + j*16 + (lane & 15);
    if (n >= Nvalid) continue;
    float bv = 0.f;
    if constexpr (EPI==1 || EPI==2 || EPI==4) bv = bias[n];
    if constexpr (EPI==6){ if (n < 512) bv = bias[n]; }
#pragma unroll
    for (int i = 0; i < 2; i++){
#pragma unroll
      for (int r = 0; r < 4; r++){
        const int m = m0 + wr*32 + i*16 + (lane>>4)*4 + r;
        const int b = m >> 4;
        float x = acc[i][j][r];
        if constexpr (EPI==0){ ((float*)Cout)[(size_t)m*ldc+n] = x; }
        if constexpr (EPI==1){ ((float*)Cout)[(size_t)m*ldc+n] = x + bv; }
        if constexpr (EPI==2){ ((u16*)Cout)[(size_t)m*ldc+n] = f2bf(geluf(x + bv)); }
        if constexpr (EPI==5){ ((u16*)Cout)[(size_t)m*ldc+n] = f2bf(x); }
        if constexpr (EPI==3){
          ((float*)Cout)[(size_t)m*ldc+n] =
              aux0[(size_t)m*256+n] + mods[(size_t)b*1536+512+n]*x;
        }
        if constexpr (EPI==4){
          float v = aux0[(size_t)m*256+n] + mods[(size_t)b*1536+1280+n]*(x + bv);
          const int pos = m & 15;
          const int c = n>>6, hr=(n>>3)&7, wrr=n&7;
          const int hh = (pos>>2)*8+hr, ww=(pos&3)*8+wrr;
          out4[(((size_t)b*4+c)*32+hh)*32+ww] = v;
        }
        if constexpr (EPI==6){
          if (n < 512){
            float dt = x + bv;
            float del = (dt > 20.f) ? dt : log1pf(__expf(dt));
            ((float*)Cout)[(size_t)m*512+n] = del;
          } else {
            out4[(size_t)m*32 + (n-512)] = x;
          }
        }
      }
    }
  }
}

// fp32 -> bf16 conversion of F_clip + 6 weight matrices, one fused kernel.
__global__ __launch_bounds__(256) void cvt_bf16(
    const float* __restrict__ clip, const float* __restrict__ fsw,
    const float* __restrict__ inp,  const float* __restrict__ xp,
    const float* __restrict__ outp, const float* __restrict__ f1,
    const float* __restrict__ f2,   u16* __restrict__ dst)
{
  const int q = blockIdx.x*256 + threadIdx.x;   // quad index (x4 elems)
  const float* s; int off;
  if      (q < 65536)  { s = clip; off = q*4; }
  else if (q < 262144) { s = fsw;  off = (q-65536)*4; }
  else if (q < 327680) { s = inp;  off = (q-262144)*4; }
  else if (q < 333824) { s = xp;   off = (q-327680)*4; }
  else if (q < 366592) { s = outp; off = (q-333824)*4; }
  else if (q < 382976) { s = f1;   off = (q-366592)*4; }
  else                 { s = f2;   off = (q-382976)*4; }
  float4 v = *(const float4*)&s[off];
  uint2 o;
  o.x = (u32)f2bf(v.x) | ((u32)f2bf(v.y)<<16);
  o.y = (u32)f2bf(v.z) | ((u32)f2bf(v.w)<<16);
  *(uint2*)&dst[(size_t)q*4] = o;
}

// Build combined x_proj weight (544 x 512) in bf16:
// rows 0..511  : Wc = dt_proj_w @ x_proj_w[:16]   (dt path folded into GEMM)
// rows 512..543: x_proj_w rows 16..47 (B and C rows)
__global__ __launch_bounds__(512) void wcomb(
    const float* __restrict__ dtw, const float* __restrict__ xpw,
    u16* __restrict__ wall)
{
  const int n = blockIdx.x;      // 0..543
  const int k = threadIdx.x;     // 0..511
  float v;
  if (n < 512){
    v = 0.f;
#pragma unroll
    for (int r=0;r<16;r++) v = fmaf(dtw[n*16+r], xpw[r*512+k], v);
  } else {
    v = xpw[(size_t)(16 + n-512)*512 + k];
  }
  wall[(size_t)n*512+k] = f2bf(v);
}

// LayerNorm + modulate. SHUF: gather via pixel shuffle, also write x0 (fp32).
template<bool SHUF>
__global__ __launch_bounds__(256) void ln_mod(
    const float* __restrict__ src, const float* __restrict__ mods,
    int sh_off, float* __restrict__ x0_out, u16* __restrict__ u_out)
{
  const int wave = threadIdx.x>>6, lane = threadIdx.x&63;
  const int m = blockIdx.x*4 + wave;
  const int b = m>>4;
  const int c0 = lane*4;
  float4 v;
  if constexpr (SHUF){
    const int pos=m&15, hb=pos>>2, wb=pos&3;
    const int c=c0>>6, hr=(c0>>3)&7, wrb=c0&7;
    v = *(const float4*)&src[(((size_t)b*4+c)*32 + hb*8+hr)*32 + wb*8 + wrb];
  } else {
    v = *(const float4*)&src[(size_t)m*256 + c0];
  }
  float s  = v.x+v.y+v.z+v.w;
  float s2 = v.x*v.x+v.y*v.y+v.z*v.z+v.w*v.w;
#pragma unroll
  for (int off=1; off<64; off<<=1){
    s  += __shfl_xor(s, off);
    s2 += __shfl_xor(s2, off);
  }
  const float mean = s*(1.f/256.f);
  const float var  = s2*(1.f/256.f) - mean*mean;
  const float rs   = rsqrtf(var + 1e-6f);
  float4 sh = *(const float4*)&mods[(size_t)b*1536 + sh_off + c0];
  float4 sc = *(const float4*)&mods[(size_t)b*1536 + sh_off + 256 + c0];
  float ux = (v.x-mean)*rs*(1.f+sc.x) + sh.x;
  float uy = (v.y-mean)*rs*(1.f+sc.y) + sh.y;
  float uz = (v.z-mean)*rs*(1.f+sc.z) + sh.z;
  float uw = (v.w-mean)*rs*(1.f+sc.w) + sh.w;
  if constexpr (SHUF) *(float4*)&x0_out[(size_t)m*256+c0] = v;
  uint2 o;
  o.x = (u32)f2bf(ux) | ((u32)f2bf(uy)<<16);
  o.y = (u32)f2bf(uz) | ((u32)f2bf(uw)<<16);
  *(uint2*)&u_out[(size_t)m*256+c0] = o;
}

// Depthwise causal conv (k=4) + SiLU, bf16 in (x-half of xz) / bf16 out.
__global__ __launch_bounds__(256) void conv_silu(
    const u16* __restrict__ xz, const float* __restrict__ cw,
    const float* __restrict__ cb, u16* __restrict__ xs)
{
  const int t = blockIdx.x*256 + threadIdx.x;
  const int b = t>>9, d = t&511;
  const u16* xp = xz + (size_t)b*16384 + d;
  float x[16];
#pragma unroll
  for (int l=0;l<16;l++) x[l] = bf2f(xp[(size_t)l*1024]);
  const float w0=cw[d*4+0], w1=cw[d*4+1], w2=cw[d*4+2], w3=cw[d*4+3];
  const float bias = cb[d];
  u16* op = xs + (size_t)b*8192 + d;
#pragma unroll
  for (int l=0;l<16;l++){
    float a = bias + w3*x[l];
    if (l>=1) a += w2*x[l-1];
    if (l>=2) a += w1*x[l-2];
    if (l>=3) a += w0*x[l-3];
    a = a*sigf(a);
    op[(size_t)l*512] = f2bf(a);
  }
}

// Selective scan v3. Block per batch (512 threads = channels).
// delta precomputed (softplus in GEMM epilogue); B/C block-uniform scalar
// loads; dA via single v_exp (exp2, pre-scaled A).
// y overwrites xs IN PLACE (same element read then written per thread per l:
// race-free, and gives K6 a dense lda=512 A-operand).
__global__ __launch_bounds__(512) void scan_kernel(
    u16* __restrict__ xs, const u16* __restrict__ xz,
    const float* __restrict__ delta, const float* __restrict__ BC,
    const float* __restrict__ A_log, const float* __restrict__ Dskip)
{
  const int b = blockIdx.x, d = threadIdx.x;
  float An2[16], h[16];
#pragma unroll
  for (int n=0;n<16;n++){
    An2[n] = -__expf(A_log[d*16+n]) * 1.44269504f;   // A * log2(e)
    h[n] = 0.f;
  }
  const float Dv = Dskip[d];
  const float* dp  = delta + (size_t)b*8192 + d;
  const float* bcp = BC + (size_t)b*512;            // (16,32) per batch, uniform
  u16* xsp = xs + (size_t)b*8192 + d;
  const u16* zp = xz + (size_t)b*16384 + 512 + d;
#pragma unroll
  for (int l=0;l<16;l++){
    const float dl = dp[(size_t)l*512];
    const float xl = bf2f(xsp[(size_t)l*512]);
    const float dx = dl*xl;
    float yv = Dv*xl;
#pragma unroll
    for (int n=0;n<16;n++){
      const float dA = EXP2F(dl*An2[n]);
      h[n] = fmaf(dA, h[n], bcp[l*32+n]*dx);
      yv = fmaf(h[n], bcp[l*32+16+n], yv);
    }
    const float zl = bf2f(zp[(size_t)l*1024]);
    yv *= zl*sigf(zl);
    xsp[(size_t)l*512] = f2bf(yv);                  // y in place of xs
  }
}

extern "C" void kernel_launch(void* const* d_in, const int* in_sizes, int n_in,
                              void* d_out, int out_size, void* d_ws, size_t ws_size,
                              hipStream_t stream)
{
  const float* F_clip    = (const float*)d_in[0];
  const float* F_content = (const float*)d_in[1];
  const float* fs_b      = (const float*)d_in[3];
  const float* conv_w    = (const float*)d_in[5];
  const float* conv_b    = (const float*)d_in[6];
  const float* x_proj_w  = (const float*)d_in[7];
  const float* dt_proj_w = (const float*)d_in[8];
  const float* dt_proj_b = (const float*)d_in[9];
  const float* A_log     = (const float*)d_in[10];
  const float* D_skip    = (const float*)d_in[11];
  const float* fc1_b     = (const float*)d_in[14];
  const float* fc2_b     = (const float*)d_in[16];
  float* out = (float*)d_out;

  float* ws = (float*)d_ws;
  float* w_mods  = ws;                     // 786432 f
  float* w_x0    = w_mods + 786432;        // 2097152 f
  float* w_x1    = w_x0   + 2097152;       // 2097152 f
  float* w_delta = w_x1   + 2097152;       // 4194304 f  (8192 x 512)
  float* w_bc    = w_delta+ 4194304;       // 262144 f   (8192 x 32)
  u16* u_bf    = (u16*)(w_bc + 262144);    // 2097152 h
  u16* xz_bf   = u_bf    + 2097152;        // 8388608 h
  u16* xs_bf   = xz_bf   + 8388608;        // 4194304 h
  u16* u2_bf   = xs_bf   + 4194304;        // 2097152 h
  u16* hmid_bf = u2_bf   + 2097152;        // 2097152 h
  u16* wall_bf = hmid_bf + 2097152;        // 278528 h   (544 x 512)
  u16* wt_bf   = wall_bf + 278528;         // 1597440 h  => total ~79.3 MB

  u16* clip_bf = wt_bf;
  u16* fsw_bf  = wt_bf + 262144;
  u16* inp_bf  = wt_bf + 1048576;
  u16* outp_bf = wt_bf + 1335296;
  u16* fc1_bf  = wt_bf + 1466368;
  u16* fc2_bf  = wt_bf + 1531904;

  // K0: fp32 -> bf16 for F_clip + all GEMM weights
  cvt_bf16<<<1560,256,0,stream>>>(F_clip, (const float*)d_in[2],
      (const float*)d_in[4], (const float*)d_in[7], (const float*)d_in[12],
      (const float*)d_in[13], (const float*)d_in[15], wt_bf);
  // K0b: combined x_proj/dt_proj weight (544 x 512)
  wcomb<<<544,512,0,stream>>>(dt_proj_w, x_proj_w, wall_bf);
  // K1: mods = F_clip @ fs_w.T + fs_b           (512 x 1536, K=512)
  gemm_mfma<1><<<dim3(24,8),256,0,stream>>>(clip_bf,512, fsw_bf,512, 512,1536,
      fs_b, w_mods,1536, nullptr,nullptr,nullptr);
  // K2: pixel shuffle + LN + modulate -> x0 (f32), u (bf16)
  ln_mod<true><<<2048,256,0,stream>>>(F_content, w_mods, 0, w_x0, u_bf);
  // K3: xz = u @ in_proj.T                      (8192 x 1024, K=256) -> bf16
  gemm_mfma<5><<<dim3(16,128),256,0,stream>>>(u_bf,256, inp_bf,256, 256,1024,
      nullptr, xz_bf,1024, nullptr,nullptr,nullptr);
  // K4: depthwise causal conv + silu -> xs (bf16)
  conv_silu<<<1024,256,0,stream>>>(xz_bf, conv_w, conv_b, xs_bf);
  // K4b: [delta | BC] = xs @ Wall.T             (8192 x 544, K=512)
  gemm_mfma<6><<<dim3(9,128),256,0,stream>>>(xs_bf,512, wall_bf,512, 512,544,
      dt_proj_b, w_delta,512, nullptr,nullptr, w_bc);
  // K5: selective scan + gate -> y (bf16, in place into xs)
  scan_kernel<<<512,512,0,stream>>>(xs_bf, xz_bf, w_delta, w_bc, A_log, D_skip);
  // K6: x1 = x0 + g_m * (y @ out_proj.T)        (8192 x 256, K=512) -> f32
  gemm_mfma<3><<<dim3(4,128),256,0,stream>>>(xs_bf,512, outp_bf,512, 512,256,
      nullptr, w_x1,256, w_x0, w_mods, nullptr);
  // K6b: LN + modulate -> u2 (bf16)
  ln_mod<false><<<2048,256,0,stream>>>(w_x1, w_mods, 768, nullptr, u2_bf);
  // K7: hmid = gelu(u2 @ fc1.T + b)             (8192 x 256, K=256) -> bf16
  gemm_mfma<2><<<dim3(4,128),256,0,stream>>>(u2_bf,256, fc1_bf,256, 256,256,
      fc1_b, hmid_bf,256, nullptr,nullptr,nullptr);
  // K8: out = unshuffle(x1 + g_p*(hmid @ fc2.T + b))
  gemm_mfma<4><<<dim3(4,128),256,0,stream>>>(hmid_bf,256, fc2_bf,256, 256,256,
      fc2_b, nullptr,256, w_x1, w_mods, out);
}

// Round 5
// 123.775 us; speedup vs baseline: 1.2432x; 1.0103x over previous
//
#include <hip/hip_runtime.h>
#include <math.h>

typedef unsigned short u16;
typedef unsigned int u32;
typedef __attribute__((ext_vector_type(8))) short bf16x8;
typedef __attribute__((ext_vector_type(4))) float f32x4;

#define AS1 __attribute__((address_space(1)))
#define AS3 __attribute__((address_space(3)))

#if __has_builtin(__builtin_amdgcn_exp2f)
#define EXP2F __builtin_amdgcn_exp2f
#else
#define EXP2F exp2f
#endif

__device__ __forceinline__ float sigf(float x){ return 1.f/(1.f+__expf(-x)); }
__device__ __forceinline__ float geluf(float x){
  float x3 = x*x*x;
  return 0.5f*x*(1.f + tanhf(0.7978845608f*(x + 0.044715f*x3)));
}
__device__ __forceinline__ float bf2f(u16 u){ return __uint_as_float(((u32)u)<<16); }
__device__ __forceinline__ u16 f2bf(float x){           // round-to-nearest-even
  u32 u = __float_as_uint(x);
  u32 r = (u + 0x7FFFu + ((u>>16)&1u)) >> 16;
  return (u16)r;
}

// ---------------------------------------------------------------------------
// bf16 MFMA GEMM: C[m][n] = sum_k A[m][k] * W[n][k]  (both K-contiguous)
// BM2 x 64 tile, BK=64, 4 waves (2x2), wave tile (BM2/2) x 32.
// Double-buffered LDS; 2-phase schedule with counted vmcnt so next-tile
// global_load_lds latency hides under MFMA (T3/T4 minimum recipe):
//   STAGE(next) ; vmcnt(NL) ; s_barrier ; COMPUTE(cur) ; lgkmcnt(0) ; s_barrier
// EPI: 0=store f32, 1=+bias f32, 2=gelu(+bias)->bf16, 5=bf16,
//      3=shuffle-gather(F_content)+g_m*acc -> f32,
//      4=x1+g_p*(acc+bias) -> inverse pixel-shuffle scatter,
//      6=combined x_proj: n<512 -> softplus(acc+dt_bias) -> bf16 delta,
//        n>=512 -> BC f32 (8192x32).
// ---------------------------------------------------------------------------
template<int BM2, int EPI>
__global__ __launch_bounds__(256) void gemm_mfma(
    const u16* __restrict__ A, int lda,
    const u16* __restrict__ W, int ldw,
    int K, int Nvalid,
    const float* __restrict__ bias,
    void* __restrict__ Cout, int ldc,
    const float* __restrict__ aux0,   // F_content (EPI3) / x1 (EPI4), fp32
    const float* __restrict__ mods,   // (512,1536) fp32
    float* __restrict__ out4)         // final output (EPI4) / BC (EPI6)
{
  constexpr int WM  = BM2/2;     // wave tile rows
  constexpr int NIf = WM/16;     // A fragments per wave (2 or 4)
  constexpr int NCA = BM2/32;    // A chunks staged per wave (2 or 4)
  __shared__ u16 Alds[2][BM2*64];
  __shared__ u16 Blds[2][64*64];
  const int tid  = threadIdx.x;
  const int lane = tid & 63, wid = tid >> 6;
  const int wr = wid >> 1, wc = wid & 1;
  const int m0 = blockIdx.y*BM2, n0 = blockIdx.x*64;
  const int ln8 = lane >> 3, lk = lane & 7;

  f32x4 acc[NIf][2];
#pragma unroll
  for (int i=0;i<NIf;i++)
#pragma unroll
    for (int j=0;j<2;j++) acc[i][j] = (f32x4){0.f,0.f,0.f,0.f};

  auto STAGE = [&](int buf, int k0){
#pragma unroll
    for (int j = 0; j < NCA; j++){
      const int c   = j*4 + wid;
      const int row = c*8 + ln8;
      const int ks  = lk ^ (row & 7);     // inverse-swizzled source k-slot
      const u16* src = A + (size_t)(m0+row)*lda + k0 + 8*ks;
      __builtin_amdgcn_global_load_lds((AS1 const void*)src,
                                       (AS3 void*)&Alds[buf][c*512], 16, 0, 0);
    }
#pragma unroll
    for (int j = 0; j < 2; j++){
      const int c   = j*4 + wid;
      const int row = c*8 + ln8;
      const int ks  = lk ^ (row & 7);
      int rn = n0 + row; if (rn > Nvalid-1) rn = Nvalid-1;
      const u16* src = W + (size_t)rn*ldw + k0 + 8*ks;
      __builtin_amdgcn_global_load_lds((AS1 const void*)src,
                                       (AS3 void*)&Blds[buf][c*512], 16, 0, 0);
    }
  };

  auto COMPUTE = [&](int buf){
#pragma unroll
    for (int kk = 0; kk < 2; kk++){
      bf16x8 af[NIf], bfr[2];
      const int ks = kk*4 + (lane >> 4);
#pragma unroll
      for (int i = 0; i < NIf; i++){
        const int row = wr*WM + i*16 + (lane & 15);
        af[i] = *(const bf16x8*)&Alds[buf][row*64 + 8*(ks ^ (row & 7))];
      }
#pragma unroll
      for (int j = 0; j < 2; j++){
        const int col = wc*32 + j*16 + (lane & 15);
        bfr[j] = *(const bf16x8*)&Blds[buf][col*64 + 8*(ks ^ (col & 7))];
      }
#pragma unroll
      for (int i = 0; i < NIf; i++)
#pragma unroll
        for (int j = 0; j < 2; j++)
          acc[i][j] = __builtin_amdgcn_mfma_f32_16x16x32_bf16(af[i], bfr[j], acc[i][j], 0, 0, 0);
    }
  };

  const int nt = K >> 6;
  STAGE(0, 0);
  int cur = 0;
  for (int t = 0; t < nt-1; ++t){
    STAGE(cur^1, (t+1)<<6);
    if constexpr (BM2 == 64) asm volatile("s_waitcnt vmcnt(4)" ::: "memory");
    else                     asm volatile("s_waitcnt vmcnt(6)" ::: "memory");
    __builtin_amdgcn_s_barrier();
    COMPUTE(cur);
    asm volatile("s_waitcnt lgkmcnt(0)" ::: "memory");
    __builtin_amdgcn_s_barrier();
    cur ^= 1;
  }
  asm volatile("s_waitcnt vmcnt(0)" ::: "memory");
  __builtin_amdgcn_s_barrier();
  COMPUTE(cur);

  // Epilogue. C/D layout: col = lane&15, row = (lane>>4)*4 + r.
#pragma unroll
  for (int j = 0; j < 2; j++){
    const int n = n0 + wc*32 + j*16 + (lane & 15);
    if (n >= Nvalid) continue;
    float bv = 0.f;
    if constexpr (EPI==1 || EPI==2 || EPI==4) bv = bias[n];
    if constexpr (EPI==6){ if (n < 512) bv = bias[n]; }
#pragma unroll
    for (int i = 0; i < NIf; i++){
#pragma unroll
      for (int r = 0; r < 4; r++){
        const int m = m0 + wr*WM + i*16 + (lane>>4)*4 + r;
        const int b = m >> 4;
        float x = acc[i][j][r];
        if constexpr (EPI==0){ ((float*)Cout)[(size_t)m*ldc+n] = x; }
        if constexpr (EPI==1){ ((float*)Cout)[(size_t)m*ldc+n] = x + bv; }
        if constexpr (EPI==2){ ((u16*)Cout)[(size_t)m*ldc+n] = f2bf(geluf(x + bv)); }
        if constexpr (EPI==5){ ((u16*)Cout)[(size_t)m*ldc+n] = f2bf(x); }
        if constexpr (EPI==3){
          // residual gathered straight from F_content via pixel shuffle
          const int pos = m & 15;
          const int c = n>>6, hr=(n>>3)&7, wrr=n&7;
          const int hh = (pos>>2)*8+hr, ww=(pos&3)*8+wrr;
          const float x0v = aux0[(((size_t)b*4+c)*32+hh)*32+ww];
          ((float*)Cout)[(size_t)m*ldc+n] = x0v + mods[(size_t)b*1536+512+n]*x;
        }
        if constexpr (EPI==4){
          float v = aux0[(size_t)m*256+n] + mods[(size_t)b*1536+1280+n]*(x + bv);
          const int pos = m & 15;
          const int c = n>>6, hr=(n>>3)&7, wrr=n&7;
          const int hh = (pos>>2)*8+hr, ww=(pos&3)*8+wrr;
          out4[(((size_t)b*4+c)*32+hh)*32+ww] = v;
        }
        if constexpr (EPI==6){
          if (n < 512){
            float dt = x + bv;
            float del = (dt > 20.f) ? dt : log1pf(__expf(dt));
            ((u16*)Cout)[(size_t)m*512+n] = f2bf(del);
          } else {
            out4[(size_t)m*32 + (n-512)] = x;
          }
        }
      }
    }
  }
}

// Setup: fp32->bf16 of F_clip + 6 weights (blocks 0..1559), plus the combined
// x_proj/dt_proj weight Wall (544x512, blocks 1560..2647):
//   rows 0..511  : Wc = dt_proj_w @ x_proj_w[:16]
//   rows 512..543: x_proj_w rows 16..47 (B and C rows)
__global__ __launch_bounds__(256) void setup_bf16(
    const float* __restrict__ clip, const float* __restrict__ fsw,
    const float* __restrict__ inp,  const float* __restrict__ xp,
    const float* __restrict__ outp, const float* __restrict__ f1,
    const float* __restrict__ f2,   const float* __restrict__ dtw,
    u16* __restrict__ dst, u16* __restrict__ wall)
{
  const int bid = blockIdx.x;
  if (bid < 1560){
    const int q = bid*256 + threadIdx.x;   // quad index (x4 elems)
    const float* s; int off;
    if      (q < 65536)  { s = clip; off = q*4; }
    else if (q < 262144) { s = fsw;  off = (q-65536)*4; }
    else if (q < 327680) { s = inp;  off = (q-262144)*4; }
    else if (q < 333824) { s = xp;   off = (q-327680)*4; }
    else if (q < 366592) { s = outp; off = (q-333824)*4; }
    else if (q < 382976) { s = f1;   off = (q-366592)*4; }
    else                 { s = f2;   off = (q-382976)*4; }
    float4 v = *(const float4*)&s[off];
    uint2 o;
    o.x = (u32)f2bf(v.x) | ((u32)f2bf(v.y)<<16);
    o.y = (u32)f2bf(v.z) | ((u32)f2bf(v.w)<<16);
    *(uint2*)&dst[(size_t)q*4] = o;
  } else {
    const int t = bid - 1560;              // 0..1087
    const int n = t >> 1;                  // 0..543
    const int k = (t & 1)*256 + threadIdx.x;
    float v;
    if (n < 512){
      v = 0.f;
#pragma unroll
      for (int r=0;r<16;r++) v = fmaf(dtw[n*16+r], xp[r*512+k], v);
    } else {
      v = xp[(size_t)(16 + n-512)*512 + k];
    }
    wall[(size_t)n*512+k] = f2bf(v);
  }
}

// LayerNorm + modulate. SHUF: gather via pixel shuffle. u output bf16.
template<bool SHUF>
__global__ __launch_bounds__(256) void ln_mod(
    const float* __restrict__ src, const float* __restrict__ mods,
    int sh_off, u16* __restrict__ u_out)
{
  const int wave = threadIdx.x>>6, lane = threadIdx.x&63;
  const int m = blockIdx.x*4 + wave;
  const int b = m>>4;
  const int c0 = lane*4;
  float4 v;
  if constexpr (SHUF){
    const int pos=m&15, hb=pos>>2, wb=pos&3;
    const int c=c0>>6, hr=(c0>>3)&7, wrb=c0&7;
    v = *(const float4*)&src[(((size_t)b*4+c)*32 + hb*8+hr)*32 + wb*8 + wrb];
  } else {
    v = *(const float4*)&src[(size_t)m*256 + c0];
  }
  float s  = v.x+v.y+v.z+v.w;
  float s2 = v.x*v.x+v.y*v.y+v.z*v.z+v.w*v.w;
#pragma unroll
  for (int off=1; off<64; off<<=1){
    s  += __shfl_xor(s, off);
    s2 += __shfl_xor(s2, off);
  }
  const float mean = s*(1.f/256.f);
  const float var  = s2*(1.f/256.f) - mean*mean;
  const float rs   = rsqrtf(var + 1e-6f);
  float4 sh = *(const float4*)&mods[(size_t)b*1536 + sh_off + c0];
  float4 sc = *(const float4*)&mods[(size_t)b*1536 + sh_off + 256 + c0];
  float ux = (v.x-mean)*rs*(1.f+sc.x) + sh.x;
  float uy = (v.y-mean)*rs*(1.f+sc.y) + sh.y;
  float uz = (v.z-mean)*rs*(1.f+sc.z) + sh.z;
  float uw = (v.w-mean)*rs*(1.f+sc.w) + sh.w;
  uint2 o;
  o.x = (u32)f2bf(ux) | ((u32)f2bf(uy)<<16);
  o.y = (u32)f2bf(uz) | ((u32)f2bf(uw)<<16);
  *(uint2*)&u_out[(size_t)m*256+c0] = o;
}

// Depthwise causal conv (k=4) + SiLU, bf16 in (x-half of xz) / bf16 out.
__global__ __launch_bounds__(256) void conv_silu(
    const u16* __restrict__ xz, const float* __restrict__ cw,
    const float* __restrict__ cb, u16* __restrict__ xs)
{
  const int t = blockIdx.x*256 + threadIdx.x;
  const int b = t>>9, d = t&511;
  const u16* xp = xz + (size_t)b*16384 + d;
  float x[16];
#pragma unroll
  for (int l=0;l<16;l++) x[l] = bf2f(xp[(size_t)l*1024]);
  const float w0=cw[d*4+0], w1=cw[d*4+1], w2=cw[d*4+2], w3=cw[d*4+3];
  const float bias = cb[d];
  u16* op = xs + (size_t)b*8192 + d;
#pragma unroll
  for (int l=0;l<16;l++){
    float a = bias + w3*x[l];
    if (l>=1) a += w2*x[l-1];
    if (l>=2) a += w1*x[l-2];
    if (l>=3) a += w0*x[l-3];
    a = a*sigf(a);
    op[(size_t)l*512] = f2bf(a);
  }
}

// Selective scan. Block per batch (512 threads = channels).
// delta precomputed bf16 (softplus in GEMM epilogue); B/C block-uniform
// scalar loads; dA via single v_exp (exp2, pre-scaled A).
// y overwrites xs IN PLACE (race-free: same element per thread).
__global__ __launch_bounds__(512) void scan_kernel(
    u16* __restrict__ xs, const u16* __restrict__ xz,
    const u16* __restrict__ delta, const float* __restrict__ BC,
    const float* __restrict__ A_log, const float* __restrict__ Dskip)
{
  const int b = blockIdx.x, d = threadIdx.x;
  float An2[16], h[16];
#pragma unroll
  for (int n=0;n<16;n++){
    An2[n] = -__expf(A_log[d*16+n]) * 1.44269504f;   // A * log2(e)
    h[n] = 0.f;
  }
  const float Dv = Dskip[d];
  const u16* dp  = delta + (size_t)b*8192 + d;
  const float* bcp = BC + (size_t)b*512;            // (16,32) per batch, uniform
  u16* xsp = xs + (size_t)b*8192 + d;
  const u16* zp = xz + (size_t)b*16384 + 512 + d;
#pragma unroll
  for (int l=0;l<16;l++){
    const float dl = bf2f(dp[(size_t)l*512]);
    const float xl = bf2f(xsp[(size_t)l*512]);
    const float dx = dl*xl;
    float yv = Dv*xl;
#pragma unroll
    for (int n=0;n<16;n++){
      const float dA = EXP2F(dl*An2[n]);
      h[n] = fmaf(dA, h[n], bcp[l*32+n]*dx);
      yv = fmaf(h[n], bcp[l*32+16+n], yv);
    }
    const float zl = bf2f(zp[(size_t)l*1024]);
    yv *= zl*sigf(zl);
    xsp[(size_t)l*512] = f2bf(yv);                  // y in place of xs
  }
}

extern "C" void kernel_launch(void* const* d_in, const int* in_sizes, int n_in,
                              void* d_out, int out_size, void* d_ws, size_t ws_size,
                              hipStream_t stream)
{
  const float* F_clip    = (const float*)d_in[0];
  const float* F_content = (const float*)d_in[1];
  const float* fs_b      = (const float*)d_in[3];
  const float* conv_w    = (const float*)d_in[5];
  const float* conv_b    = (const float*)d_in[6];
  const float* x_proj_w  = (const float*)d_in[7];
  const float* dt_proj_w = (const float*)d_in[8];
  const float* dt_proj_b = (const float*)d_in[9];
  const float* A_log     = (const float*)d_in[10];
  const float* D_skip    = (const float*)d_in[11];
  const float* fc1_b     = (const float*)d_in[14];
  const float* fc2_b     = (const float*)d_in[16];
  float* out = (float*)d_out;

  float* ws = (float*)d_ws;
  float* w_mods  = ws;                     // 786432 f
  float* w_x1    = w_mods + 786432;        // 2097152 f
  float* w_bc    = w_x1   + 2097152;       // 262144 f   (8192 x 32)
  u16* delta_bf = (u16*)(w_bc + 262144);   // 4194304 h  (8192 x 512)
  u16* u_bf    = delta_bf + 4194304;       // 2097152 h
  u16* xz_bf   = u_bf    + 2097152;        // 8388608 h
  u16* xs_bf   = xz_bf   + 8388608;        // 4194304 h
  u16* u2_bf   = xs_bf   + 4194304;        // 2097152 h
  u16* hmid_bf = u2_bf   + 2097152;        // 2097152 h
  u16* wall_bf = hmid_bf + 2097152;        // 278528 h   (544 x 512)
  u16* wt_bf   = wall_bf + 278528;         // 1597440 h  => ~63 MB total

  u16* clip_bf = wt_bf;
  u16* fsw_bf  = wt_bf + 262144;
  u16* inp_bf  = wt_bf + 1048576;
  u16* outp_bf = wt_bf + 1335296;
  u16* fc1_bf  = wt_bf + 1466368;
  u16* fc2_bf  = wt_bf + 1531904;

  // K0: fp32 -> bf16 conversions + combined x_proj/dt_proj weight
  setup_bf16<<<2648,256,0,stream>>>(F_clip, (const float*)d_in[2],
      (const float*)d_in[4], x_proj_w, (const float*)d_in[12],
      (const float*)d_in[13], (const float*)d_in[15], dt_proj_w,
      wt_bf, wall_bf);
  // K1: mods = F_clip @ fs_w.T + fs_b           (512 x 1536, K=512)
  gemm_mfma<64,1><<<dim3(24,8),256,0,stream>>>(clip_bf,512, fsw_bf,512, 512,1536,
      fs_b, w_mods,1536, nullptr,nullptr,nullptr);
  // K2: pixel shuffle + LN + modulate -> u (bf16)
  ln_mod<true><<<2048,256,0,stream>>>(F_content, w_mods, 0, u_bf);
  // K3: xz = u @ in_proj.T                      (8192 x 1024, K=256) -> bf16
  gemm_mfma<128,5><<<dim3(16,64),256,0,stream>>>(u_bf,256, inp_bf,256, 256,1024,
      nullptr, xz_bf,1024, nullptr,nullptr,nullptr);
  // K4: depthwise causal conv + silu -> xs (bf16)
  conv_silu<<<1024,256,0,stream>>>(xz_bf, conv_w, conv_b, xs_bf);
  // K4b: [delta | BC] = xs @ Wall.T             (8192 x 544, K=512)
  gemm_mfma<128,6><<<dim3(9,64),256,0,stream>>>(xs_bf,512, wall_bf,512, 512,544,
      dt_proj_b, delta_bf,512, nullptr,nullptr, w_bc);
  // K5: selective scan + gate -> y (bf16, in place into xs)
  scan_kernel<<<512,512,0,stream>>>(xs_bf, xz_bf, delta_bf, w_bc, A_log, D_skip);
  // K6: x1 = shuffle(F_content) + g_m*(y @ out_proj.T)  (8192x256, K=512) f32
  gemm_mfma<64,3><<<dim3(4,128),256,0,stream>>>(xs_bf,512, outp_bf,512, 512,256,
      nullptr, w_x1,256, F_content, w_mods, nullptr);
  // K6b: LN + modulate -> u2 (bf16)
  ln_mod<false><<<2048,256,0,stream>>>(w_x1, w_mods, 768, u2_bf);
  // K7: hmid = gelu(u2 @ fc1.T + b)             (8192 x 256, K=256) -> bf16
  gemm_mfma<64,2><<<dim3(4,128),256,0,stream>>>(u2_bf,256, fc1_bf,256, 256,256,
      fc1_b, hmid_bf,256, nullptr,nullptr,nullptr);
  // K8: out = unshuffle(x1 + g_p*(hmid @ fc2.T + b))
  gemm_mfma<64,4><<<dim3(4,128),256,0,stream>>>(hmid_bf,256, fc2_bf,256, 256,256,
      fc2_b, nullptr,256, w_x1, w_mods, out);
}

// Round 6
// 120.929 us; speedup vs baseline: 1.2725x; 1.0235x over previous
//
#include <hip/hip_runtime.h>
#include <math.h>

typedef unsigned short u16;
typedef unsigned int u32;
typedef __attribute__((ext_vector_type(8))) short bf16x8;
typedef __attribute__((ext_vector_type(4))) float f32x4;

#define AS1 __attribute__((address_space(1)))
#define AS3 __attribute__((address_space(3)))

#if __has_builtin(__builtin_amdgcn_exp2f)
#define EXP2F __builtin_amdgcn_exp2f
#else
#define EXP2F exp2f
#endif

__device__ __forceinline__ float sigf(float x){ return 1.f/(1.f+__expf(-x)); }
__device__ __forceinline__ float geluf(float x){
  float x3 = x*x*x;
  return 0.5f*x*(1.f + tanhf(0.7978845608f*(x + 0.044715f*x3)));
}
__device__ __forceinline__ float bf2f(u16 u){ return __uint_as_float(((u32)u)<<16); }
__device__ __forceinline__ u16 f2bf(float x){           // round-to-nearest-even
  u32 u = __float_as_uint(x);
  u32 r = (u + 0x7FFFu + ((u>>16)&1u)) >> 16;
  return (u16)r;
}
__device__ __forceinline__ void gload16(const u16* src, u16* dst){
  __builtin_amdgcn_global_load_lds((AS1 const void*)src, (AS3 void*)dst, 16, 0, 0);
}

// ---------------------------------------------------------------------------
// bf16 MFMA GEMM: C[m][n] = sum_k A[m][k] * W[n][k]  (both K-contiguous)
// BM2 x 64 tile, BK=64, 4 waves (2x2), wave tile (BM2/2) x 32.
// Double-buffered LDS, counted-vmcnt 2-phase schedule.
// EPI: 1=+bias f32, 5=bf16,
//      6=combined x_proj: n<512 -> softplus(acc+dt_bias) -> bf16 delta,
//        n>=512 -> BC f32 (8192x32).
// ---------------------------------------------------------------------------
template<int BM2, int EPI>
__global__ __launch_bounds__(256) void gemm_mfma(
    const u16* __restrict__ A, int lda,
    const u16* __restrict__ W, int ldw,
    int K, int Nvalid,
    const float* __restrict__ bias,
    void* __restrict__ Cout, int ldc,
    float* __restrict__ out4)         // BC (EPI6)
{
  constexpr int WM  = BM2/2;     // wave tile rows
  constexpr int NIf = WM/16;     // A fragments per wave (2 or 4)
  constexpr int NCA = BM2/32;    // A chunks staged per wave (2 or 4)
  __shared__ u16 Alds[2][BM2*64];
  __shared__ u16 Blds[2][64*64];
  const int tid  = threadIdx.x;
  const int lane = tid & 63, wid = tid >> 6;
  const int wr = wid >> 1, wc = wid & 1;
  const int m0 = blockIdx.y*BM2, n0 = blockIdx.x*64;
  const int ln8 = lane >> 3, lk = lane & 7;

  f32x4 acc[NIf][2];
#pragma unroll
  for (int i=0;i<NIf;i++)
#pragma unroll
    for (int j=0;j<2;j++) acc[i][j] = (f32x4){0.f,0.f,0.f,0.f};

  auto STAGE = [&](int buf, int k0){
#pragma unroll
    for (int j = 0; j < NCA; j++){
      const int c   = j*4 + wid;
      const int row = c*8 + ln8;
      const int ks  = lk ^ (row & 7);     // inverse-swizzled source k-slot
      gload16(A + (size_t)(m0+row)*lda + k0 + 8*ks, &Alds[buf][c*512]);
    }
#pragma unroll
    for (int j = 0; j < 2; j++){
      const int c   = j*4 + wid;
      const int row = c*8 + ln8;
      const int ks  = lk ^ (row & 7);
      int rn = n0 + row; if (rn > Nvalid-1) rn = Nvalid-1;
      gload16(W + (size_t)rn*ldw + k0 + 8*ks, &Blds[buf][c*512]);
    }
  };

  auto COMPUTE = [&](int buf){
#pragma unroll
    for (int kk = 0; kk < 2; kk++){
      bf16x8 af[NIf], bfr[2];
      const int ks = kk*4 + (lane >> 4);
#pragma unroll
      for (int i = 0; i < NIf; i++){
        const int row = wr*WM + i*16 + (lane & 15);
        af[i] = *(const bf16x8*)&Alds[buf][row*64 + 8*(ks ^ (row & 7))];
      }
#pragma unroll
      for (int j = 0; j < 2; j++){
        const int col = wc*32 + j*16 + (lane & 15);
        bfr[j] = *(const bf16x8*)&Blds[buf][col*64 + 8*(ks ^ (col & 7))];
      }
#pragma unroll
      for (int i = 0; i < NIf; i++)
#pragma unroll
        for (int j = 0; j < 2; j++)
          acc[i][j] = __builtin_amdgcn_mfma_f32_16x16x32_bf16(af[i], bfr[j], acc[i][j], 0, 0, 0);
    }
  };

  const int nt = K >> 6;
  STAGE(0, 0);
  int cur = 0;
  for (int t = 0; t < nt-1; ++t){
    STAGE(cur^1, (t+1)<<6);
    if constexpr (BM2 == 64) asm volatile("s_waitcnt vmcnt(4)" ::: "memory");
    else                     asm volatile("s_waitcnt vmcnt(6)" ::: "memory");
    __builtin_amdgcn_s_barrier();
    COMPUTE(cur);
    asm volatile("s_waitcnt lgkmcnt(0)" ::: "memory");
    __builtin_amdgcn_s_barrier();
    cur ^= 1;
  }
  asm volatile("s_waitcnt vmcnt(0)" ::: "memory");
  __builtin_amdgcn_s_barrier();
  COMPUTE(cur);

  // Epilogue. C/D layout: col = lane&15, row = (lane>>4)*4 + r.
#pragma unroll
  for (int j = 0; j < 2; j++){
    const int n = n0 + wc*32 + j*16 + (lane & 15);
    if (n >= Nvalid) continue;
    float bv = 0.f;
    if constexpr (EPI==1) bv = bias[n];
    if constexpr (EPI==6){ if (n < 512) bv = bias[n]; }
#pragma unroll
    for (int i = 0; i < NIf; i++){
#pragma unroll
      for (int r = 0; r < 4; r++){
        const int m = m0 + wr*WM + i*16 + (lane>>4)*4 + r;
        float x = acc[i][j][r];
        if constexpr (EPI==1){ ((float*)Cout)[(size_t)m*ldc+n] = x + bv; }
        if constexpr (EPI==5){ ((u16*)Cout)[(size_t)m*ldc+n] = f2bf(x); }
        if constexpr (EPI==6){
          if (n < 512){
            float dt = x + bv;
            float del = (dt > 20.f) ? dt : log1pf(__expf(dt));
            ((u16*)Cout)[(size_t)m*512+n] = f2bf(del);
          } else {
            out4[(size_t)m*32 + (n-512)] = x;
          }
        }
      }
    }
  }
}

// ---------------------------------------------------------------------------
// F1: x1 = shuffle(F_content) + g_m*(y @ Wo.T); u2 = modulate(ln(x1),sh_p,sc_p)
// 256 blocks x 512 threads. BM=32 rows, full N=256. 8 waves: wr=wid>>2 (rows),
// wc=wid&3 (64-col slice). Wave tile 16x64 -> acc[4]. K=512 (8 steps, dbuf).
// ---------------------------------------------------------------------------
__global__ __launch_bounds__(512) void fused_out_ln(
    const u16* __restrict__ Y, const u16* __restrict__ Wo,
    const float* __restrict__ Fc, const float* __restrict__ mods,
    float* __restrict__ x1, u16* __restrict__ u2)
{
  __shared__ u16 Albuf[2][32*64];      // 8 KB
  __shared__ u16 Wbuf[2][256*64];      // 64 KB
  __shared__ float redS[32][4], redQ[32][4];
  const int tid = threadIdx.x;
  const int lane = tid & 63, wid = tid >> 6;
  const int wr = wid >> 2, wc = wid & 3;
  const int m0 = blockIdx.x * 32;
  const int ln8 = lane>>3, lk = lane&7;
  const int g = lane>>4, c16 = lane&15;

  f32x4 acc[4];
#pragma unroll
  for (int j=0;j<4;j++) acc[j] = (f32x4){0.f,0.f,0.f,0.f};

  auto STAGE = [&](int buf, int k0){
    if (wid < 4){
      const int row = wid*8 + ln8;
      const int ks = lk ^ (row&7);
      gload16(Y + (size_t)(m0+row)*512 + k0 + 8*ks, &Albuf[buf][wid*512]);
    }
#pragma unroll
    for (int j=0;j<4;j++){
      const int c = j*8 + wid;
      const int row = c*8 + ln8;          // 0..255 = output col
      const int ks = lk ^ (row&7);
      gload16(Wo + (size_t)row*512 + k0 + 8*ks, &Wbuf[buf][c*512]);
    }
  };
  auto COMPUTE = [&](int buf){
#pragma unroll
    for (int kk=0;kk<2;kk++){
      const int ks = kk*4 + g;
      const int row = wr*16 + c16;
      bf16x8 af = *(const bf16x8*)&Albuf[buf][row*64 + 8*(ks^(row&7))];
#pragma unroll
      for (int j=0;j<4;j++){
        const int col = wc*64 + j*16 + c16;
        bf16x8 bf = *(const bf16x8*)&Wbuf[buf][col*64 + 8*(ks^(col&7))];
        acc[j] = __builtin_amdgcn_mfma_f32_16x16x32_bf16(af, bf, acc[j], 0,0,0);
      }
    }
  };

  STAGE(0,0);
  int cur = 0;
  for (int t=0;t<7;++t){
    STAGE(cur^1, (t+1)*64);
    if (wid<4) asm volatile("s_waitcnt vmcnt(5)" ::: "memory");
    else       asm volatile("s_waitcnt vmcnt(4)" ::: "memory");
    __builtin_amdgcn_s_barrier();
    COMPUTE(cur);
    asm volatile("s_waitcnt lgkmcnt(0)" ::: "memory");
    __builtin_amdgcn_s_barrier();
    cur ^= 1;
  }
  asm volatile("s_waitcnt vmcnt(0)" ::: "memory");
  __builtin_amdgcn_s_barrier();
  COMPUTE(cur);

  // epilogue: residual + store x1, then LN stats, then u2
  float xv[4][4];
  float s[4] = {0.f,0.f,0.f,0.f}, q[4] = {0.f,0.f,0.f,0.f};
#pragma unroll
  for (int j=0;j<4;j++){
    const int n = wc*64 + j*16 + c16;
#pragma unroll
    for (int r=0;r<4;r++){
      const int ml = wr*16 + g*4 + r;
      const int m = m0 + ml, b = m>>4;
      const int pos = m&15, c = n>>6, hr = (n>>3)&7, wrr = n&7;
      const int hh = (pos>>2)*8+hr, ww = (pos&3)*8+wrr;
      const float x0v = Fc[(((size_t)b*4+c)*32+hh)*32+ww];
      const float v = x0v + mods[(size_t)b*1536+512+n]*acc[j][r];
      xv[j][r] = v;
      x1[(size_t)m*256+n] = v;
      s[r] += v; q[r] += v*v;
    }
  }
#pragma unroll
  for (int off=1; off<16; off<<=1){
#pragma unroll
    for (int r=0;r<4;r++){
      s[r] += __shfl_xor(s[r], off);
      q[r] += __shfl_xor(q[r], off);
    }
  }
  if (c16==0){
#pragma unroll
    for (int r=0;r<4;r++){
      redS[wr*16+g*4+r][wc] = s[r];
      redQ[wr*16+g*4+r][wc] = q[r];
    }
  }
  __syncthreads();
  float mean[4], rs[4];
#pragma unroll
  for (int r=0;r<4;r++){
    const int ml = wr*16 + g*4 + r;
    const float S = redS[ml][0]+redS[ml][1]+redS[ml][2]+redS[ml][3];
    const float Q = redQ[ml][0]+redQ[ml][1]+redQ[ml][2]+redQ[ml][3];
    mean[r] = S*(1.f/256.f);
    const float var = Q*(1.f/256.f) - mean[r]*mean[r];
    rs[r] = rsqrtf(var + 1e-6f);
  }
#pragma unroll
  for (int j=0;j<4;j++){
    const int n = wc*64 + j*16 + c16;
#pragma unroll
    for (int r=0;r<4;r++){
      const int m = m0 + wr*16 + g*4 + r, b = m>>4;
      const float u2v = (xv[j][r]-mean[r])*rs[r]*(1.f+mods[(size_t)b*1536+1024+n])
                        + mods[(size_t)b*1536+768+n];
      u2[(size_t)m*256+n] = f2bf(u2v);
    }
  }
}

// ---------------------------------------------------------------------------
// F2: h = gelu(u2 @ W1.T + b1) [kept in LDS]; out = unshuffle(x1 + g_p*(h @ W2.T + b2))
// Same geometry as F1. K=256 each (4 steps).
// ---------------------------------------------------------------------------
__global__ __launch_bounds__(512) void fused_mlp(
    const u16* __restrict__ U2, const u16* __restrict__ W1,
    const u16* __restrict__ W2, const float* __restrict__ b1v,
    const float* __restrict__ b2v, const float* __restrict__ x1,
    const float* __restrict__ mods, float* __restrict__ out)
{
  __shared__ u16 Albuf[2][32*64];      // 8 KB
  __shared__ u16 Wbuf[2][256*64];      // 64 KB
  __shared__ u16 hm[32*256];           // 16 KB (swizzled A-layout)
  const int tid = threadIdx.x;
  const int lane = tid & 63, wid = tid >> 6;
  const int wr = wid >> 2, wc = wid & 3;
  const int m0 = blockIdx.x * 32;
  const int ln8 = lane>>3, lk = lane&7;
  const int g = lane>>4, c16 = lane&15;

  f32x4 acc[4];
#pragma unroll
  for (int j=0;j<4;j++) acc[j] = (f32x4){0.f,0.f,0.f,0.f};

  auto STAGE1 = [&](int buf, int k0){
    if (wid < 4){
      const int row = wid*8 + ln8;
      const int ks = lk ^ (row&7);
      gload16(U2 + (size_t)(m0+row)*256 + k0 + 8*ks, &Albuf[buf][wid*512]);
    }
#pragma unroll
    for (int j=0;j<4;j++){
      const int c = j*8 + wid;
      const int row = c*8 + ln8;
      const int ks = lk ^ (row&7);
      gload16(W1 + (size_t)row*256 + k0 + 8*ks, &Wbuf[buf][c*512]);
    }
  };
  auto COMPUTE1 = [&](int buf){
#pragma unroll
    for (int kk=0;kk<2;kk++){
      const int ks = kk*4 + g;
      const int row = wr*16 + c16;
      bf16x8 af = *(const bf16x8*)&Albuf[buf][row*64 + 8*(ks^(row&7))];
#pragma unroll
      for (int j=0;j<4;j++){
        const int col = wc*64 + j*16 + c16;
        bf16x8 bf = *(const bf16x8*)&Wbuf[buf][col*64 + 8*(ks^(col&7))];
        acc[j] = __builtin_amdgcn_mfma_f32_16x16x32_bf16(af, bf, acc[j], 0,0,0);
      }
    }
  };
  auto STAGE2 = [&](int buf, int k0){
#pragma unroll
    for (int j=0;j<4;j++){
      const int c = j*8 + wid;
      const int row = c*8 + ln8;
      const int ks = lk ^ (row&7);
      gload16(W2 + (size_t)row*256 + k0 + 8*ks, &Wbuf[buf][c*512]);
    }
  };
  auto COMPUTE2 = [&](int buf, int t){
#pragma unroll
    for (int kk=0;kk<2;kk++){
      const int ks = kk*4 + g;
      const int row = wr*16 + c16;
      bf16x8 af = *(const bf16x8*)&hm[row*256 + t*64 + 8*(ks^(row&7))];
#pragma unroll
      for (int j=0;j<4;j++){
        const int col = wc*64 + j*16 + c16;
        bf16x8 bf = *(const bf16x8*)&Wbuf[buf][col*64 + 8*(ks^(col&7))];
        acc[j] = __builtin_amdgcn_mfma_f32_16x16x32_bf16(af, bf, acc[j], 0,0,0);
      }
    }
  };

  // ---- phase 1: fc1 ----
  STAGE1(0,0);
  int cur = 0;
  for (int t=0;t<3;++t){
    STAGE1(cur^1, (t+1)*64);
    if (wid<4) asm volatile("s_waitcnt vmcnt(5)" ::: "memory");
    else       asm volatile("s_waitcnt vmcnt(4)" ::: "memory");
    __builtin_amdgcn_s_barrier();
    COMPUTE1(cur);
    asm volatile("s_waitcnt lgkmcnt(0)" ::: "memory");
    __builtin_amdgcn_s_barrier();
    cur ^= 1;
  }
  asm volatile("s_waitcnt vmcnt(0)" ::: "memory");
  __builtin_amdgcn_s_barrier();
  COMPUTE1(cur);

  // epilogue 1: gelu -> hm (swizzled so COMPUTE2 A-reads match)
#pragma unroll
  for (int j=0;j<4;j++){
    const int n = wc*64 + j*16 + c16;
    const float bv = b1v[n];
#pragma unroll
    for (int r=0;r<4;r++){
      const int ml = wr*16 + g*4 + r;
      const float h = geluf(acc[j][r] + bv);
      const int slot = j*2 + (c16>>3);
      hm[ml*256 + wc*64 + 8*(slot ^ (ml&7)) + (c16&7)] = f2bf(h);
    }
  }
#pragma unroll
  for (int j=0;j<4;j++) acc[j] = (f32x4){0.f,0.f,0.f,0.f};

  // ---- phase 2: fc2 ----
  STAGE2(0,0);
  asm volatile("s_waitcnt lgkmcnt(0)" ::: "memory");   // hm writes done
  __builtin_amdgcn_s_barrier();
  cur = 0;
  for (int t=0;t<3;++t){
    STAGE2(cur^1, (t+1)*64);
    asm volatile("s_waitcnt vmcnt(4)" ::: "memory");
    __builtin_amdgcn_s_barrier();
    COMPUTE2(cur, t);
    asm volatile("s_waitcnt lgkmcnt(0)" ::: "memory");
    __builtin_amdgcn_s_barrier();
    cur ^= 1;
  }
  asm volatile("s_waitcnt vmcnt(0)" ::: "memory");
  __builtin_amdgcn_s_barrier();
  COMPUTE2(cur, 3);

  // epilogue 2: residual + unshuffle scatter
#pragma unroll
  for (int j=0;j<4;j++){
    const int n = wc*64 + j*16 + c16;
    const float bv = b2v[n];
#pragma unroll
    for (int r=0;r<4;r++){
      const int m = m0 + wr*16 + g*4 + r, b = m>>4;
      const float v = x1[(size_t)m*256+n]
                    + mods[(size_t)b*1536+1280+n]*(acc[j][r] + bv);
      const int pos = m&15, c = n>>6, hr=(n>>3)&7, wrr=n&7;
      const int hh = (pos>>2)*8+hr, ww = (pos&3)*8+wrr;
      out[(((size_t)b*4+c)*32+hh)*32+ww] = v;
    }
  }
}

// Setup: fp32->bf16 of F_clip + 6 weights (blocks 0..1559), plus the combined
// x_proj/dt_proj weight Wall (544x512, blocks 1560..2647)
__global__ __launch_bounds__(256) void setup_bf16(
    const float* __restrict__ clip, const float* __restrict__ fsw,
    const float* __restrict__ inp,  const float* __restrict__ xp,
    const float* __restrict__ outp, const float* __restrict__ f1,
    const float* __restrict__ f2,   const float* __restrict__ dtw,
    u16* __restrict__ dst, u16* __restrict__ wall)
{
  const int bid = blockIdx.x;
  if (bid < 1560){
    const int q = bid*256 + threadIdx.x;   // quad index (x4 elems)
    const float* s; int off;
    if      (q < 65536)  { s = clip; off = q*4; }
    else if (q < 262144) { s = fsw;  off = (q-65536)*4; }
    else if (q < 327680) { s = inp;  off = (q-262144)*4; }
    else if (q < 333824) { s = xp;   off = (q-327680)*4; }
    else if (q < 366592) { s = outp; off = (q-333824)*4; }
    else if (q < 382976) { s = f1;   off = (q-366592)*4; }
    else                 { s = f2;   off = (q-382976)*4; }
    float4 v = *(const float4*)&s[off];
    uint2 o;
    o.x = (u32)f2bf(v.x) | ((u32)f2bf(v.y)<<16);
    o.y = (u32)f2bf(v.z) | ((u32)f2bf(v.w)<<16);
    *(uint2*)&dst[(size_t)q*4] = o;
  } else {
    const int t = bid - 1560;              // 0..1087
    const int n = t >> 1;                  // 0..543
    const int k = (t & 1)*256 + threadIdx.x;
    float v;
    if (n < 512){
      v = 0.f;
#pragma unroll
      for (int r=0;r<16;r++) v = fmaf(dtw[n*16+r], xp[r*512+k], v);
    } else {
      v = xp[(size_t)(16 + n-512)*512 + k];
    }
    wall[(size_t)n*512+k] = f2bf(v);
  }
}

// LayerNorm + modulate with pixel-shuffle gather. u output bf16.
__global__ __launch_bounds__(256) void ln_mod_shuf(
    const float* __restrict__ src, const float* __restrict__ mods,
    u16* __restrict__ u_out)
{
  const int wave = threadIdx.x>>6, lane = threadIdx.x&63;
  const int m = blockIdx.x*4 + wave;
  const int b = m>>4;
  const int c0 = lane*4;
  const int pos=m&15, hb=pos>>2, wb=pos&3;
  const int c=c0>>6, hr=(c0>>3)&7, wrb=c0&7;
  float4 v = *(const float4*)&src[(((size_t)b*4+c)*32 + hb*8+hr)*32 + wb*8 + wrb];
  float s  = v.x+v.y+v.z+v.w;
  float s2 = v.x*v.x+v.y*v.y+v.z*v.z+v.w*v.w;
#pragma unroll
  for (int off=1; off<64; off<<=1){
    s  += __shfl_xor(s, off);
    s2 += __shfl_xor(s2, off);
  }
  const float mean = s*(1.f/256.f);
  const float var  = s2*(1.f/256.f) - mean*mean;
  const float rs   = rsqrtf(var + 1e-6f);
  float4 sh = *(const float4*)&mods[(size_t)b*1536 + c0];
  float4 sc = *(const float4*)&mods[(size_t)b*1536 + 256 + c0];
  float ux = (v.x-mean)*rs*(1.f+sc.x) + sh.x;
  float uy = (v.y-mean)*rs*(1.f+sc.y) + sh.y;
  float uz = (v.z-mean)*rs*(1.f+sc.z) + sh.z;
  float uw = (v.w-mean)*rs*(1.f+sc.w) + sh.w;
  uint2 o;
  o.x = (u32)f2bf(ux) | ((u32)f2bf(uy)<<16);
  o.y = (u32)f2bf(uz) | ((u32)f2bf(uw)<<16);
  *(uint2*)&u_out[(size_t)m*256+c0] = o;
}

// Depthwise causal conv (k=4) + SiLU, bf16 in (x-half of xz) / bf16 out.
__global__ __launch_bounds__(256) void conv_silu(
    const u16* __restrict__ xz, const float* __restrict__ cw,
    const float* __restrict__ cb, u16* __restrict__ xs)
{
  const int t = blockIdx.x*256 + threadIdx.x;
  const int b = t>>9, d = t&511;
  const u16* xp = xz + (size_t)b*16384 + d;
  float x[16];
#pragma unroll
  for (int l=0;l<16;l++) x[l] = bf2f(xp[(size_t)l*1024]);
  const float w0=cw[d*4+0], w1=cw[d*4+1], w2=cw[d*4+2], w3=cw[d*4+3];
  const float bias = cb[d];
  u16* op = xs + (size_t)b*8192 + d;
#pragma unroll
  for (int l=0;l<16;l++){
    float a = bias + w3*x[l];
    if (l>=1) a += w2*x[l-1];
    if (l>=2) a += w1*x[l-2];
    if (l>=3) a += w0*x[l-3];
    a = a*sigf(a);
    op[(size_t)l*512] = f2bf(a);
  }
}

// Selective scan. Block per batch (512 threads = channels).
// delta precomputed bf16 (softplus in GEMM epilogue); B/C block-uniform
// scalar loads; dA via single v_exp (exp2, pre-scaled A).
// y overwrites xs IN PLACE (race-free: same element per thread).
__global__ __launch_bounds__(512) void scan_kernel(
    u16* __restrict__ xs, const u16* __restrict__ xz,
    const u16* __restrict__ delta, const float* __restrict__ BC,
    const float* __restrict__ A_log, const float* __restrict__ Dskip)
{
  const int b = blockIdx.x, d = threadIdx.x;
  float An2[16], h[16];
#pragma unroll
  for (int n=0;n<16;n++){
    An2[n] = -__expf(A_log[d*16+n]) * 1.44269504f;   // A * log2(e)
    h[n] = 0.f;
  }
  const float Dv = Dskip[d];
  const u16* dp  = delta + (size_t)b*8192 + d;
  const float* bcp = BC + (size_t)b*512;            // (16,32) per batch, uniform
  u16* xsp = xs + (size_t)b*8192 + d;
  const u16* zp = xz + (size_t)b*16384 + 512 + d;
#pragma unroll
  for (int l=0;l<16;l++){
    const float dl = bf2f(dp[(size_t)l*512]);
    const float xl = bf2f(xsp[(size_t)l*512]);
    const float dx = dl*xl;
    float yv = Dv*xl;
#pragma unroll
    for (int n=0;n<16;n++){
      const float dA = EXP2F(dl*An2[n]);
      h[n] = fmaf(dA, h[n], bcp[l*32+n]*dx);
      yv = fmaf(h[n], bcp[l*32+16+n], yv);
    }
    const float zl = bf2f(zp[(size_t)l*1024]);
    yv *= zl*sigf(zl);
    xsp[(size_t)l*512] = f2bf(yv);                  // y in place of xs
  }
}

extern "C" void kernel_launch(void* const* d_in, const int* in_sizes, int n_in,
                              void* d_out, int out_size, void* d_ws, size_t ws_size,
                              hipStream_t stream)
{
  const float* F_clip    = (const float*)d_in[0];
  const float* F_content = (const float*)d_in[1];
  const float* fs_b      = (const float*)d_in[3];
  const float* conv_w    = (const float*)d_in[5];
  const float* conv_b    = (const float*)d_in[6];
  const float* x_proj_w  = (const float*)d_in[7];
  const float* dt_proj_w = (const float*)d_in[8];
  const float* dt_proj_b = (const float*)d_in[9];
  const float* A_log     = (const float*)d_in[10];
  const float* D_skip    = (const float*)d_in[11];
  const float* fc1_b     = (const float*)d_in[14];
  const float* fc2_b     = (const float*)d_in[16];
  float* out = (float*)d_out;

  float* ws = (float*)d_ws;
  float* w_mods  = ws;                     // 786432 f
  float* w_x1    = w_mods + 786432;        // 2097152 f
  float* w_bc    = w_x1   + 2097152;       // 262144 f   (8192 x 32)
  u16* delta_bf = (u16*)(w_bc + 262144);   // 4194304 h  (8192 x 512)
  u16* u_bf    = delta_bf + 4194304;       // 2097152 h
  u16* xz_bf   = u_bf    + 2097152;        // 8388608 h
  u16* xs_bf   = xz_bf   + 8388608;        // 4194304 h
  u16* u2_bf   = xs_bf   + 4194304;        // 2097152 h
  u16* wall_bf = u2_bf   + 2097152;        // 278528 h   (544 x 512)
  u16* wt_bf   = wall_bf + 278528;         // 1597440 h

  u16* clip_bf = wt_bf;
  u16* fsw_bf  = wt_bf + 262144;
  u16* inp_bf  = wt_bf + 1048576;
  u16* outp_bf = wt_bf + 1335296;
  u16* fc1_bf  = wt_bf + 1466368;
  u16* fc2_bf  = wt_bf + 1531904;

  // K0: fp32 -> bf16 conversions + combined x_proj/dt_proj weight
  setup_bf16<<<2648,256,0,stream>>>(F_clip, (const float*)d_in[2],
      (const float*)d_in[4], x_proj_w, (const float*)d_in[12],
      (const float*)d_in[13], (const float*)d_in[15], dt_proj_w,
      wt_bf, wall_bf);
  // K1: mods = F_clip @ fs_w.T + fs_b           (512 x 1536, K=512)
  gemm_mfma<64,1><<<dim3(24,8),256,0,stream>>>(clip_bf,512, fsw_bf,512, 512,1536,
      fs_b, w_mods,1536, nullptr);
  // K2: pixel shuffle + LN + modulate -> u (bf16)
  ln_mod_shuf<<<2048,256,0,stream>>>(F_content, w_mods, u_bf);
  // K3: xz = u @ in_proj.T                      (8192 x 1024, K=256) -> bf16
  gemm_mfma<128,5><<<dim3(16,64),256,0,stream>>>(u_bf,256, inp_bf,256, 256,1024,
      nullptr, xz_bf,1024, nullptr);
  // K4: depthwise causal conv + silu -> xs (bf16)
  conv_silu<<<1024,256,0,stream>>>(xz_bf, conv_w, conv_b, xs_bf);
  // K4b: [delta | BC] = xs @ Wall.T             (8192 x 544, K=512)
  gemm_mfma<128,6><<<dim3(9,64),256,0,stream>>>(xs_bf,512, wall_bf,512, 512,544,
      dt_proj_b, delta_bf,512, w_bc);
  // K5: selective scan + gate -> y (bf16, in place into xs)
  scan_kernel<<<512,512,0,stream>>>(xs_bf, xz_bf, delta_bf, w_bc, A_log, D_skip);
  // F1: out_proj + residual + LN + modulate -> x1 (f32), u2 (bf16)
  fused_out_ln<<<256,512,0,stream>>>(xs_bf, outp_bf, F_content, w_mods,
                                     w_x1, u2_bf);
  // F2: fc1 + gelu + fc2 + residual + unshuffle -> out
  fused_mlp<<<256,512,0,stream>>>(u2_bf, fc1_bf, fc2_bf, fc1_b, fc2_b,
                                  w_x1, w_mods, out);
}

// Round 7
// 114.449 us; speedup vs baseline: 1.3446x; 1.0566x over previous
//
#include <hip/hip_runtime.h>
#include <math.h>

typedef unsigned short u16;
typedef unsigned int u32;
typedef __attribute__((ext_vector_type(8))) short bf16x8;
typedef __attribute__((ext_vector_type(4))) float f32x4;

#define AS1 __attribute__((address_space(1)))
#define AS3 __attribute__((address_space(3)))

#if __has_builtin(__builtin_amdgcn_exp2f)
#define EXP2F __builtin_amdgcn_exp2f
#else
#define EXP2F exp2f
#endif

__device__ __forceinline__ float sigf(float x){ return 1.f/(1.f+__expf(-x)); }
__device__ __forceinline__ float geluf(float x){
  float x3 = x*x*x;
  return 0.5f*x*(1.f + tanhf(0.7978845608f*(x + 0.044715f*x3)));
}
__device__ __forceinline__ float bf2f(u16 u){ return __uint_as_float(((u32)u)<<16); }
__device__ __forceinline__ u16 f2bf(float x){           // round-to-nearest-even
  u32 u = __float_as_uint(x);
  u32 r = (u + 0x7FFFu + ((u>>16)&1u)) >> 16;
  return (u16)r;
}
__device__ __forceinline__ void gload16(const u16* src, u16* dst){
  __builtin_amdgcn_global_load_lds((AS1 const void*)src, (AS3 void*)dst, 16, 0, 0);
}

// ---------------------------------------------------------------------------
// bf16 MFMA GEMM: C[m][n] = sum_k A[m][k] * W[n][k]  (both K-contiguous)
// BM2 x 64 tile, BK=64, 4 waves (2x2), wave tile (BM2/2) x 32.
// Double-buffered LDS, counted-vmcnt 2-phase schedule.
// EPI: 1=+bias f32,
//      6=combined x_proj: n<512 -> softplus(acc+dt_bias) -> bf16 delta,
//        n>=512 -> BC f32 (8192x32),
//      7=in_proj: n<512 -> causal conv4 + silu -> xq bf16 (conv along l via
//        in-register r-shifts + shfl(lane-16));  n>=512 -> zq bf16 (dense).
// ---------------------------------------------------------------------------
template<int BM2, int EPI>
__global__ __launch_bounds__(256) void gemm_mfma(
    const u16* __restrict__ A, int lda,
    const u16* __restrict__ W, int ldw,
    int K, int Nvalid,
    const float* __restrict__ bias,
    void* __restrict__ Cout, int ldc,
    float* __restrict__ out4,         // BC (EPI6) / zq (EPI7, cast)
    const float* __restrict__ cw)     // conv weights (EPI7)
{
  constexpr int WM  = BM2/2;     // wave tile rows
  constexpr int NIf = WM/16;     // A fragments per wave (2 or 4)
  constexpr int NCA = BM2/32;    // A chunks staged per wave (2 or 4)
  __shared__ u16 Alds[2][BM2*64];
  __shared__ u16 Blds[2][64*64];
  const int tid  = threadIdx.x;
  const int lane = tid & 63, wid = tid >> 6;
  const int wr = wid >> 1, wc = wid & 1;
  const int m0 = blockIdx.y*BM2, n0 = blockIdx.x*64;
  const int ln8 = lane >> 3, lk = lane & 7;

  f32x4 acc[NIf][2];
#pragma unroll
  for (int i=0;i<NIf;i++)
#pragma unroll
    for (int j=0;j<2;j++) acc[i][j] = (f32x4){0.f,0.f,0.f,0.f};

  auto STAGE = [&](int buf, int k0){
#pragma unroll
    for (int j = 0; j < NCA; j++){
      const int c   = j*4 + wid;
      const int row = c*8 + ln8;
      const int ks  = lk ^ (row & 7);     // inverse-swizzled source k-slot
      gload16(A + (size_t)(m0+row)*lda + k0 + 8*ks, &Alds[buf][c*512]);
    }
#pragma unroll
    for (int j = 0; j < 2; j++){
      const int c   = j*4 + wid;
      const int row = c*8 + ln8;
      const int ks  = lk ^ (row & 7);
      int rn = n0 + row; if (rn > Nvalid-1) rn = Nvalid-1;
      gload16(W + (size_t)rn*ldw + k0 + 8*ks, &Blds[buf][c*512]);
    }
  };

  auto COMPUTE = [&](int buf){
#pragma unroll
    for (int kk = 0; kk < 2; kk++){
      bf16x8 af[NIf], bfr[2];
      const int ks = kk*4 + (lane >> 4);
#pragma unroll
      for (int i = 0; i < NIf; i++){
        const int row = wr*WM + i*16 + (lane & 15);
        af[i] = *(const bf16x8*)&Alds[buf][row*64 + 8*(ks ^ (row & 7))];
      }
#pragma unroll
      for (int j = 0; j < 2; j++){
        const int col = wc*32 + j*16 + (lane & 15);
        bfr[j] = *(const bf16x8*)&Blds[buf][col*64 + 8*(ks ^ (col & 7))];
      }
#pragma unroll
      for (int i = 0; i < NIf; i++)
#pragma unroll
        for (int j = 0; j < 2; j++)
          acc[i][j] = __builtin_amdgcn_mfma_f32_16x16x32_bf16(af[i], bfr[j], acc[i][j], 0, 0, 0);
    }
  };

  const int nt = K >> 6;
  STAGE(0, 0);
  int cur = 0;
  for (int t = 0; t < nt-1; ++t){
    STAGE(cur^1, (t+1)<<6);
    if constexpr (BM2 == 64) asm volatile("s_waitcnt vmcnt(4)" ::: "memory");
    else                     asm volatile("s_waitcnt vmcnt(6)" ::: "memory");
    __builtin_amdgcn_s_barrier();
    COMPUTE(cur);
    asm volatile("s_waitcnt lgkmcnt(0)" ::: "memory");
    __builtin_amdgcn_s_barrier();
    cur ^= 1;
  }
  asm volatile("s_waitcnt vmcnt(0)" ::: "memory");
  __builtin_amdgcn_s_barrier();
  COMPUTE(cur);

  // Epilogues. C/D layout: col = lane&15, row = (lane>>4)*4 + r.
  const int c16 = lane & 15, g = lane >> 4;
  if constexpr (EPI==7){
    if (n0 < 512){
#pragma unroll
      for (int j=0;j<2;j++){
        const int n = n0 + wc*32 + j*16 + c16;
        const float4 cwv = *(const float4*)&cw[n*4];
        const float cb0 = bias[n];
        u16* xqp = (u16*)Cout;
#pragma unroll
        for (int i=0;i<NIf;i++){
          const float v0=acc[i][j][0], v1=acc[i][j][1], v2=acc[i][j][2], v3=acc[i][j][3];
          float p1 = __shfl(v1, (lane+48)&63);
          float p2 = __shfl(v2, (lane+48)&63);
          float p3 = __shfl(v3, (lane+48)&63);
          if (g==0){ p1=0.f; p2=0.f; p3=0.f; }
          float o0 = cb0 + cwv.w*v0 + cwv.z*p3 + cwv.y*p2 + cwv.x*p1;
          float o1 = cb0 + cwv.w*v1 + cwv.z*v0 + cwv.y*p3 + cwv.x*p2;
          float o2 = cb0 + cwv.w*v2 + cwv.z*v1 + cwv.y*v0 + cwv.x*p3;
          float o3 = cb0 + cwv.w*v3 + cwv.z*v2 + cwv.y*v1 + cwv.x*v0;
          o0 *= sigf(o0); o1 *= sigf(o1); o2 *= sigf(o2); o3 *= sigf(o3);
          const int mB = m0 + wr*WM + i*16 + g*4;
          xqp[(size_t)(mB+0)*512+n] = f2bf(o0);
          xqp[(size_t)(mB+1)*512+n] = f2bf(o1);
          xqp[(size_t)(mB+2)*512+n] = f2bf(o2);
          xqp[(size_t)(mB+3)*512+n] = f2bf(o3);
        }
      }
    } else {
      u16* zqp = (u16*)(void*)out4;
#pragma unroll
      for (int j=0;j<2;j++){
        const int n = n0 + wc*32 + j*16 + c16 - 512;
#pragma unroll
        for (int i=0;i<NIf;i++){
#pragma unroll
          for (int r=0;r<4;r++){
            const int m = m0 + wr*WM + i*16 + g*4 + r;
            zqp[(size_t)m*512+n] = f2bf(acc[i][j][r]);
          }
        }
      }
    }
    return;
  }
#pragma unroll
  for (int j = 0; j < 2; j++){
    const int n = n0 + wc*32 + j*16 + c16;
    if (n >= Nvalid) continue;
    float bv = 0.f;
    if constexpr (EPI==1) bv = bias[n];
    if constexpr (EPI==6){ if (n < 512) bv = bias[n]; }
#pragma unroll
    for (int i = 0; i < NIf; i++){
#pragma unroll
      for (int r = 0; r < 4; r++){
        const int m = m0 + wr*WM + i*16 + g*4 + r;
        float x = acc[i][j][r];
        if constexpr (EPI==1){ ((float*)Cout)[(size_t)m*ldc+n] = x + bv; }
        if constexpr (EPI==6){
          if (n < 512){
            float dt = x + bv;
            float del = (dt > 20.f) ? dt : log1pf(__expf(dt));
            ((u16*)Cout)[(size_t)m*512+n] = f2bf(del);
          } else {
            out4[(size_t)m*32 + (n-512)] = x;
          }
        }
      }
    }
  }
}

// ---------------------------------------------------------------------------
// TAIL: x1 = shuffle(Fc) + g_m*(y @ Wo.T)  [kept in regs]
//       u2 = modulate(ln(x1))              [kept in LDS, swizzled]
//       h  = gelu(u2 @ W1.T + b1)          [kept in LDS, swizzled]
//       out= unshuffle(x1 + g_p*(h @ W2.T + b2))
// 256 blocks x 512 threads, BM=32 rows, full N=256. 8 waves: wr=wid>>2,
// wc=wid&3. Wave tile 16x64 -> acc[4].
// ---------------------------------------------------------------------------
__global__ __launch_bounds__(512) void tail_fused(
    const u16* __restrict__ Y, const u16* __restrict__ Wo,
    const u16* __restrict__ W1, const u16* __restrict__ W2,
    const float* __restrict__ Fc, const float* __restrict__ mods,
    const float* __restrict__ b1v, const float* __restrict__ b2v,
    float* __restrict__ out)
{
  __shared__ u16 Albuf[2][32*64];      // 8 KB
  __shared__ u16 Wbuf[2][256*64];      // 64 KB
  __shared__ u16 u2l[32*256];          // 16 KB (swizzled A-layout)
  __shared__ u16 hm[32*256];           // 16 KB (swizzled A-layout)
  __shared__ float redS[32][4], redQ[32][4];
  const int tid = threadIdx.x;
  const int lane = tid & 63, wid = tid >> 6;
  const int wr = wid >> 2, wc = wid & 3;
  const int m0 = blockIdx.x * 32;
  const int ln8 = lane>>3, lk = lane&7;
  const int g = lane>>4, c16 = lane&15;

  f32x4 acc[4];
#pragma unroll
  for (int j=0;j<4;j++) acc[j] = (f32x4){0.f,0.f,0.f,0.f};

  auto STAGE_A = [&](int buf, int k0){
    if (wid < 4){
      const int row = wid*8 + ln8;
      const int ks = lk ^ (row&7);
      gload16(Y + (size_t)(m0+row)*512 + k0 + 8*ks, &Albuf[buf][wid*512]);
    }
#pragma unroll
    for (int j=0;j<4;j++){
      const int c = j*8 + wid;
      const int row = c*8 + ln8;
      const int ks = lk ^ (row&7);
      gload16(Wo + (size_t)row*512 + k0 + 8*ks, &Wbuf[buf][c*512]);
    }
  };
  auto STAGE_W = [&](const u16* Wp, int buf, int k0){
#pragma unroll
    for (int j=0;j<4;j++){
      const int c = j*8 + wid;
      const int row = c*8 + ln8;
      const int ks = lk ^ (row&7);
      gload16(Wp + (size_t)row*256 + k0 + 8*ks, &Wbuf[buf][c*512]);
    }
  };
  auto COMPUTE_A = [&](int buf){
#pragma unroll
    for (int kk=0;kk<2;kk++){
      const int ks = kk*4 + g;
      const int row = wr*16 + c16;
      bf16x8 af = *(const bf16x8*)&Albuf[buf][row*64 + 8*(ks^(row&7))];
#pragma unroll
      for (int j=0;j<4;j++){
        const int col = wc*64 + j*16 + c16;
        bf16x8 bf = *(const bf16x8*)&Wbuf[buf][col*64 + 8*(ks^(col&7))];
        acc[j] = __builtin_amdgcn_mfma_f32_16x16x32_bf16(af, bf, acc[j], 0,0,0);
      }
    }
  };
  auto COMPUTE_L = [&](const u16* Am, int buf, int t){
#pragma unroll
    for (int kk=0;kk<2;kk++){
      const int ks = kk*4 + g;
      const int row = wr*16 + c16;
      bf16x8 af = *(const bf16x8*)&Am[row*256 + t*64 + 8*(ks^(row&7))];
#pragma unroll
      for (int j=0;j<4;j++){
        const int col = wc*64 + j*16 + c16;
        bf16x8 bf = *(const bf16x8*)&Wbuf[buf][col*64 + 8*(ks^(col&7))];
        acc[j] = __builtin_amdgcn_mfma_f32_16x16x32_bf16(af, bf, acc[j], 0,0,0);
      }
    }
  };

  // ---- phase A: out_proj (K=512) ----
  STAGE_A(0,0);
  int cur = 0;
  for (int t=0;t<7;++t){
    STAGE_A(cur^1, (t+1)*64);
    if (wid<4) asm volatile("s_waitcnt vmcnt(5)" ::: "memory");
    else       asm volatile("s_waitcnt vmcnt(4)" ::: "memory");
    __builtin_amdgcn_s_barrier();
    COMPUTE_A(cur);
    asm volatile("s_waitcnt lgkmcnt(0)" ::: "memory");
    __builtin_amdgcn_s_barrier();
    cur ^= 1;
  }
  asm volatile("s_waitcnt vmcnt(0)" ::: "memory");
  __builtin_amdgcn_s_barrier();
  COMPUTE_A(cur);

  // epilogue A: residual x1 (regs) + LN stats
  float xv[4][4];
  float s[4] = {0.f,0.f,0.f,0.f}, q[4] = {0.f,0.f,0.f,0.f};
#pragma unroll
  for (int j=0;j<4;j++){
    const int n = wc*64 + j*16 + c16;
#pragma unroll
    for (int r=0;r<4;r++){
      const int ml = wr*16 + g*4 + r;
      const int m = m0 + ml, b = m>>4;
      const int pos = m&15, c = n>>6, hr = (n>>3)&7, wrr = n&7;
      const int hh = (pos>>2)*8+hr, ww = (pos&3)*8+wrr;
      const float x0v = Fc[(((size_t)b*4+c)*32+hh)*32+ww];
      const float v = x0v + mods[(size_t)b*1536+512+n]*acc[j][r];
      xv[j][r] = v;
      s[r] += v; q[r] += v*v;
    }
  }
#pragma unroll
  for (int off=1; off<16; off<<=1){
#pragma unroll
    for (int r=0;r<4;r++){
      s[r] += __shfl_xor(s[r], off);
      q[r] += __shfl_xor(q[r], off);
    }
  }
  if (c16==0){
#pragma unroll
    for (int r=0;r<4;r++){
      redS[wr*16+g*4+r][wc] = s[r];
      redQ[wr*16+g*4+r][wc] = q[r];
    }
  }
  __syncthreads();
  float mean[4], rs[4];
#pragma unroll
  for (int r=0;r<4;r++){
    const int ml = wr*16 + g*4 + r;
    const float S = redS[ml][0]+redS[ml][1]+redS[ml][2]+redS[ml][3];
    const float Q = redQ[ml][0]+redQ[ml][1]+redQ[ml][2]+redQ[ml][3];
    mean[r] = S*(1.f/256.f);
    const float var = Q*(1.f/256.f) - mean[r]*mean[r];
    rs[r] = rsqrtf(var + 1e-6f);
  }
  // u2 -> LDS (swizzled so COMPUTE_L A-reads match)
#pragma unroll
  for (int j=0;j<4;j++){
    const int n = wc*64 + j*16 + c16;
#pragma unroll
    for (int r=0;r<4;r++){
      const int ml = wr*16 + g*4 + r;
      const int m = m0 + ml, b = m>>4;
      const float u2v = (xv[j][r]-mean[r])*rs[r]*(1.f+mods[(size_t)b*1536+1024+n])
                        + mods[(size_t)b*1536+768+n];
      const int slot = j*2 + (c16>>3);
      u2l[ml*256 + wc*64 + 8*(slot ^ (ml&7)) + (c16&7)] = f2bf(u2v);
    }
  }
#pragma unroll
  for (int j=0;j<4;j++) acc[j] = (f32x4){0.f,0.f,0.f,0.f};
  __syncthreads();

  // ---- phase B: fc1 (K=256) ----
  STAGE_W(W1, 0, 0);
  cur = 0;
  for (int t=0;t<3;++t){
    STAGE_W(W1, cur^1, (t+1)*64);
    asm volatile("s_waitcnt vmcnt(4)" ::: "memory");
    __builtin_amdgcn_s_barrier();
    COMPUTE_L(u2l, cur, t);
    asm volatile("s_waitcnt lgkmcnt(0)" ::: "memory");
    __builtin_amdgcn_s_barrier();
    cur ^= 1;
  }
  asm volatile("s_waitcnt vmcnt(0)" ::: "memory");
  __builtin_amdgcn_s_barrier();
  COMPUTE_L(u2l, cur, 3);

  // epilogue B: gelu -> hm (swizzled)
#pragma unroll
  for (int j=0;j<4;j++){
    const int n = wc*64 + j*16 + c16;
    const float bv = b1v[n];
#pragma unroll
    for (int r=0;r<4;r++){
      const int ml = wr*16 + g*4 + r;
      const float h = geluf(acc[j][r] + bv);
      const int slot = j*2 + (c16>>3);
      hm[ml*256 + wc*64 + 8*(slot ^ (ml&7)) + (c16&7)] = f2bf(h);
    }
  }
#pragma unroll
  for (int j=0;j<4;j++) acc[j] = (f32x4){0.f,0.f,0.f,0.f};
  __syncthreads();

  // ---- phase C: fc2 (K=256) ----
  STAGE_W(W2, 0, 0);
  cur = 0;
  for (int t=0;t<3;++t){
    STAGE_W(W2, cur^1, (t+1)*64);
    asm volatile("s_waitcnt vmcnt(4)" ::: "memory");
    __builtin_amdgcn_s_barrier();
    COMPUTE_L(hm, cur, t);
    asm volatile("s_waitcnt lgkmcnt(0)" ::: "memory");
    __builtin_amdgcn_s_barrier();
    cur ^= 1;
  }
  asm volatile("s_waitcnt vmcnt(0)" ::: "memory");
  __builtin_amdgcn_s_barrier();
  COMPUTE_L(hm, cur, 3);

  // epilogue C: residual (regs) + unshuffle scatter
#pragma unroll
  for (int j=0;j<4;j++){
    const int n = wc*64 + j*16 + c16;
    const float bv = b2v[n];
#pragma unroll
    for (int r=0;r<4;r++){
      const int m = m0 + wr*16 + g*4 + r, b = m>>4;
      const float v = xv[j][r] + mods[(size_t)b*1536+1280+n]*(acc[j][r] + bv);
      const int pos = m&15, c = n>>6, hr=(n>>3)&7, wrr=n&7;
      const int hh = (pos>>2)*8+hr, ww = (pos&3)*8+wrr;
      out[(((size_t)b*4+c)*32+hh)*32+ww] = v;
    }
  }
}

// Setup: fp32->bf16 of F_clip + 6 weights (blocks 0..1559), plus the combined
// x_proj/dt_proj weight Wall (544x512, blocks 1560..2647)
__global__ __launch_bounds__(256) void setup_bf16(
    const float* __restrict__ clip, const float* __restrict__ fsw,
    const float* __restrict__ inp,  const float* __restrict__ xp,
    const float* __restrict__ outp, const float* __restrict__ f1,
    const float* __restrict__ f2,   const float* __restrict__ dtw,
    u16* __restrict__ dst, u16* __restrict__ wall)
{
  const int bid = blockIdx.x;
  if (bid < 1560){
    const int q = bid*256 + threadIdx.x;   // quad index (x4 elems)
    const float* s; int off;
    if      (q < 65536)  { s = clip; off = q*4; }
    else if (q < 262144) { s = fsw;  off = (q-65536)*4; }
    else if (q < 327680) { s = inp;  off = (q-262144)*4; }
    else if (q < 333824) { s = xp;   off = (q-327680)*4; }
    else if (q < 366592) { s = outp; off = (q-333824)*4; }
    else if (q < 382976) { s = f1;   off = (q-366592)*4; }
    else                 { s = f2;   off = (q-382976)*4; }
    float4 v = *(const float4*)&s[off];
    uint2 o;
    o.x = (u32)f2bf(v.x) | ((u32)f2bf(v.y)<<16);
    o.y = (u32)f2bf(v.z) | ((u32)f2bf(v.w)<<16);
    *(uint2*)&dst[(size_t)q*4] = o;
  } else {
    const int t = bid - 1560;              // 0..1087
    const int n = t >> 1;                  // 0..543
    const int k = (t & 1)*256 + threadIdx.x;
    float v;
    if (n < 512){
      v = 0.f;
#pragma unroll
      for (int r=0;r<16;r++) v = fmaf(dtw[n*16+r], xp[r*512+k], v);
    } else {
      v = xp[(size_t)(16 + n-512)*512 + k];
    }
    wall[(size_t)n*512+k] = f2bf(v);
  }
}

// LayerNorm + modulate with pixel-shuffle gather. u output bf16.
__global__ __launch_bounds__(256) void ln_mod_shuf(
    const float* __restrict__ src, const float* __restrict__ mods,
    u16* __restrict__ u_out)
{
  const int wave = threadIdx.x>>6, lane = threadIdx.x&63;
  const int m = blockIdx.x*4 + wave;
  const int b = m>>4;
  const int c0 = lane*4;
  const int pos=m&15, hb=pos>>2, wb=pos&3;
  const int c=c0>>6, hr=(c0>>3)&7, wrb=c0&7;
  float4 v = *(const float4*)&src[(((size_t)b*4+c)*32 + hb*8+hr)*32 + wb*8 + wrb];
  float s  = v.x+v.y+v.z+v.w;
  float s2 = v.x*v.x+v.y*v.y+v.z*v.z+v.w*v.w;
#pragma unroll
  for (int off=1; off<64; off<<=1){
    s  += __shfl_xor(s, off);
    s2 += __shfl_xor(s2, off);
  }
  const float mean = s*(1.f/256.f);
  const float var  = s2*(1.f/256.f) - mean*mean;
  const float rs   = rsqrtf(var + 1e-6f);
  float4 sh = *(const float4*)&mods[(size_t)b*1536 + c0];
  float4 sc = *(const float4*)&mods[(size_t)b*1536 + 256 + c0];
  float ux = (v.x-mean)*rs*(1.f+sc.x) + sh.x;
  float uy = (v.y-mean)*rs*(1.f+sc.y) + sh.y;
  float uz = (v.z-mean)*rs*(1.f+sc.z) + sh.z;
  float uw = (v.w-mean)*rs*(1.f+sc.w) + sh.w;
  uint2 o;
  o.x = (u32)f2bf(ux) | ((u32)f2bf(uy)<<16);
  o.y = (u32)f2bf(uz) | ((u32)f2bf(uw)<<16);
  *(uint2*)&u_out[(size_t)m*256+c0] = o;
}

// Selective scan. Block per batch (512 threads = channels).
// delta precomputed bf16 (softplus in GEMM epilogue); B/C block-uniform
// scalar loads; dA via single v_exp (exp2, pre-scaled A).
// y overwrites xq IN PLACE (race-free: same element per thread).
__global__ __launch_bounds__(512) void scan_kernel(
    u16* __restrict__ xq, const u16* __restrict__ zq,
    const u16* __restrict__ delta, const float* __restrict__ BC,
    const float* __restrict__ A_log, const float* __restrict__ Dskip)
{
  const int b = blockIdx.x, d = threadIdx.x;
  float An2[16], h[16];
#pragma unroll
  for (int n=0;n<16;n++){
    An2[n] = -__expf(A_log[d*16+n]) * 1.44269504f;   // A * log2(e)
    h[n] = 0.f;
  }
  const float Dv = Dskip[d];
  const u16* dp  = delta + (size_t)b*8192 + d;
  const float* bcp = BC + (size_t)b*512;            // (16,32) per batch, uniform
  u16* xsp = xq + (size_t)b*8192 + d;
  const u16* zp = zq + (size_t)b*8192 + d;
#pragma unroll
  for (int l=0;l<16;l++){
    const float dl = bf2f(dp[(size_t)l*512]);
    const float xl = bf2f(xsp[(size_t)l*512]);
    const float dx = dl*xl;
    float yv = Dv*xl;
#pragma unroll
    for (int n=0;n<16;n++){
      const float dA = EXP2F(dl*An2[n]);
      h[n] = fmaf(dA, h[n], bcp[l*32+n]*dx);
      yv = fmaf(h[n], bcp[l*32+16+n], yv);
    }
    const float zl = bf2f(zp[(size_t)l*512]);
    yv *= zl*sigf(zl);
    xsp[(size_t)l*512] = f2bf(yv);                  // y in place of xq
  }
}

extern "C" void kernel_launch(void* const* d_in, const int* in_sizes, int n_in,
                              void* d_out, int out_size, void* d_ws, size_t ws_size,
                              hipStream_t stream)
{
  const float* F_clip    = (const float*)d_in[0];
  const float* F_content = (const float*)d_in[1];
  const float* fs_b      = (const float*)d_in[3];
  const float* conv_w    = (const float*)d_in[5];
  const float* conv_b    = (const float*)d_in[6];
  const float* x_proj_w  = (const float*)d_in[7];
  const float* dt_proj_w = (const float*)d_in[8];
  const float* dt_proj_b = (const float*)d_in[9];
  const float* A_log     = (const float*)d_in[10];
  const float* D_skip    = (const float*)d_in[11];
  const float* fc1_b     = (const float*)d_in[14];
  const float* fc2_b     = (const float*)d_in[16];
  float* out = (float*)d_out;

  float* ws = (float*)d_ws;
  float* w_mods  = ws;                     // 786432 f
  float* w_bc    = w_mods + 786432;        // 262144 f   (8192 x 32)
  u16* delta_bf = (u16*)(w_bc + 262144);   // 4194304 h  (8192 x 512)
  u16* u_bf    = delta_bf + 4194304;       // 2097152 h
  u16* xq_bf   = u_bf    + 2097152;        // 4194304 h  (8192 x 512)
  u16* zq_bf   = xq_bf   + 4194304;        // 4194304 h  (8192 x 512)
  u16* wall_bf = zq_bf   + 4194304;        // 278528 h   (544 x 512)
  u16* wt_bf   = wall_bf + 278528;         // 1597440 h  => ~37 MB total

  u16* clip_bf = wt_bf;
  u16* fsw_bf  = wt_bf + 262144;
  u16* inp_bf  = wt_bf + 1048576;
  u16* outp_bf = wt_bf + 1335296;
  u16* fc1_bf  = wt_bf + 1466368;
  u16* fc2_bf  = wt_bf + 1531904;

  // K0: fp32 -> bf16 conversions + combined x_proj/dt_proj weight
  setup_bf16<<<2648,256,0,stream>>>(F_clip, (const float*)d_in[2],
      (const float*)d_in[4], x_proj_w, (const float*)d_in[12],
      (const float*)d_in[13], (const float*)d_in[15], dt_proj_w,
      wt_bf, wall_bf);
  // K1: mods = F_clip @ fs_w.T + fs_b           (512 x 1536, K=512)
  gemm_mfma<64,1><<<dim3(24,8),256,0,stream>>>(clip_bf,512, fsw_bf,512, 512,1536,
      fs_b, w_mods,1536, nullptr, nullptr);
  // K2: pixel shuffle + LN + modulate -> u (bf16)
  ln_mod_shuf<<<2048,256,0,stream>>>(F_content, w_mods, u_bf);
  // K3: in_proj + causal conv4 + silu        (8192 x 1024, K=256)
  //     x-half -> xq (conv'd), z-half -> zq (dense)
  gemm_mfma<128,7><<<dim3(16,64),256,0,stream>>>(u_bf,256, inp_bf,256, 256,1024,
      conv_b, xq_bf,512, (float*)(void*)zq_bf, conv_w);
  // K4b: [delta | BC] = xq @ Wall.T             (8192 x 544, K=512)
  gemm_mfma<128,6><<<dim3(9,64),256,0,stream>>>(xq_bf,512, wall_bf,512, 512,544,
      dt_proj_b, delta_bf,512, w_bc, nullptr);
  // K5: selective scan + gate -> y (bf16, in place into xq)
  scan_kernel<<<512,512,0,stream>>>(xq_bf, zq_bf, delta_bf, w_bc, A_log, D_skip);
  // TAIL: out_proj + residual + LN + MLP + residual + unshuffle -> out
  tail_fused<<<256,512,0,stream>>>(xq_bf, outp_bf, fc1_bf, fc2_bf,
      F_content, w_mods, fc1_b, fc2_b, out);
}

// Round 8
// 102.063 us; speedup vs baseline: 1.5077x; 1.1214x over previous
//
#include <hip/hip_runtime.h>
#include <math.h>

typedef unsigned short u16;
typedef unsigned int u32;
typedef __attribute__((ext_vector_type(8))) short bf16x8;
typedef __attribute__((ext_vector_type(4))) float f32x4;

#define AS1 __attribute__((address_space(1)))
#define AS3 __attribute__((address_space(3)))

#if __has_builtin(__builtin_amdgcn_exp2f)
#define EXP2F __builtin_amdgcn_exp2f
#else
#define EXP2F exp2f
#endif

__device__ __forceinline__ float sigf(float x){ return 1.f/(1.f+__expf(-x)); }
__device__ __forceinline__ float geluf(float x){
  float x3 = x*x*x;
  return 0.5f*x*(1.f + tanhf(0.7978845608f*(x + 0.044715f*x3)));
}
__device__ __forceinline__ float bf2f(u16 u){ return __uint_as_float(((u32)u)<<16); }
__device__ __forceinline__ u16 f2bf(float x){           // round-to-nearest-even
  u32 u = __float_as_uint(x);
  u32 r = (u + 0x7FFFu + ((u>>16)&1u)) >> 16;
  return (u16)r;
}
__device__ __forceinline__ void gload16(const u16* src, u16* dst){
  __builtin_amdgcn_global_load_lds((AS1 const void*)src, (AS3 void*)dst, 16, 0, 0);
}

// ---------------------------------------------------------------------------
// K1: mods = F_clip @ fs_w.T + fs_b  (512 x 1536, K=512). 64x64 tile, dbuf.
// ---------------------------------------------------------------------------
__global__ __launch_bounds__(256) void gemm_mods(
    const u16* __restrict__ A, const u16* __restrict__ W,
    const float* __restrict__ bias, float* __restrict__ C)
{
  __shared__ u16 Alds[2][64*64];
  __shared__ u16 Blds[2][64*64];
  const int tid  = threadIdx.x;
  const int lane = tid & 63, wid = tid >> 6;
  const int wr = wid >> 1, wc = wid & 1;
  const int m0 = blockIdx.y*64, n0 = blockIdx.x*64;
  const int ln8 = lane >> 3, lk = lane & 7;

  f32x4 acc[2][2];
#pragma unroll
  for (int i=0;i<2;i++)
#pragma unroll
    for (int j=0;j<2;j++) acc[i][j] = (f32x4){0.f,0.f,0.f,0.f};

  auto STAGE = [&](int buf, int k0){
#pragma unroll
    for (int j = 0; j < 2; j++){
      const int c   = j*4 + wid;
      const int row = c*8 + ln8;
      const int ks  = lk ^ (row & 7);
      gload16(A + (size_t)(m0+row)*512 + k0 + 8*ks, &Alds[buf][c*512]);
      gload16(W + (size_t)(n0+row)*512 + k0 + 8*ks, &Blds[buf][c*512]);
    }
  };
  auto COMPUTE = [&](int buf){
#pragma unroll
    for (int kk = 0; kk < 2; kk++){
      bf16x8 af[2], bfr[2];
      const int ks = kk*4 + (lane >> 4);
#pragma unroll
      for (int i = 0; i < 2; i++){
        const int row = wr*32 + i*16 + (lane & 15);
        af[i]  = *(const bf16x8*)&Alds[buf][row*64 + 8*(ks ^ (row & 7))];
        bfr[i] = *(const bf16x8*)&Blds[buf][row*64 + 8*(ks ^ (row & 7))];
      }
      // note: bfr uses col = wc*32 + i*16 + (lane&15)
#pragma unroll
      for (int i = 0; i < 2; i++){
        const int col = wc*32 + i*16 + (lane & 15);
        bfr[i] = *(const bf16x8*)&Blds[buf][col*64 + 8*(ks ^ (col & 7))];
      }
#pragma unroll
      for (int i = 0; i < 2; i++)
#pragma unroll
        for (int j = 0; j < 2; j++)
          acc[i][j] = __builtin_amdgcn_mfma_f32_16x16x32_bf16(af[i], bfr[j], acc[i][j], 0, 0, 0);
    }
  };

  STAGE(0, 0);
  int cur = 0;
  for (int t = 0; t < 7; ++t){
    STAGE(cur^1, (t+1)<<6);
    asm volatile("s_waitcnt vmcnt(4)" ::: "memory");
    __builtin_amdgcn_s_barrier();
    COMPUTE(cur);
    asm volatile("s_waitcnt lgkmcnt(0)" ::: "memory");
    __builtin_amdgcn_s_barrier();
    cur ^= 1;
  }
  asm volatile("s_waitcnt vmcnt(0)" ::: "memory");
  __builtin_amdgcn_s_barrier();
  COMPUTE(cur);

  const int c16 = lane & 15, g = lane >> 4;
#pragma unroll
  for (int j = 0; j < 2; j++){
    const int n = n0 + wc*32 + j*16 + c16;
    const float bv = bias[n];
#pragma unroll
    for (int i = 0; i < 2; i++)
#pragma unroll
      for (int r = 0; r < 4; r++){
        const int m = m0 + wr*32 + i*16 + g*4 + r;
        C[(size_t)m*1536+n] = acc[i][j][r] + bv;
      }
  }
}

// ---------------------------------------------------------------------------
// MAMBA CORE: one block = 2 batches (32 rows). 512 threads = 8 waves.
//  P0: LN1+modulate (pixel-shuffle gather) -> u_lds [32][256] (swizzled)
//  P1: in_proj GEMM (A=u_lds, B=W_in streamed global->reg), conv4+silu via
//      shfl -> xq_lds [32][512] (swizzled); z-half -> silu(z) -> zs_lds
//  P2: x_proj GEMM (A=xq_lds, B=Wall streamed) -> softplus -> delta_lds,
//      BC -> bc_lds
//  P3: scan (thread = channel, both batches) -> y global (bf16)
// Only 3 barriers total; no per-K-step sync.
// ---------------------------------------------------------------------------
__global__ __launch_bounds__(512) void mamba_core(
    const float* __restrict__ Fc, const float* __restrict__ mods,
    const u16* __restrict__ Win, const u16* __restrict__ Wall,
    const float* __restrict__ cw, const float* __restrict__ cb,
    const float* __restrict__ dtb, const float* __restrict__ A_log,
    const float* __restrict__ Dskip, u16* __restrict__ Yout)
{
  __shared__ u16 u_lds[32*256];      // 16 KB, swizzled
  __shared__ u16 xq_lds[32*512];     // 32 KB, swizzled
  __shared__ u16 zs_lds[32*512];     // 32 KB, linear (silu(z))
  __shared__ u16 delta_lds[32*512];  // 32 KB, linear
  __shared__ float bc_lds[32*32];    // 4 KB
  const int tid = threadIdx.x;
  const int lane = tid & 63, wid = tid >> 6;
  const int g = lane >> 4, c16 = lane & 15;
  const int blk = blockIdx.x;        // 0..255
  const int b0 = blk*2;

  // ---- P0: LN + modulate -> u_lds ----
  {
    const int row = tid >> 4;        // 0..31
    const int kq  = tid & 15;        // 16 cols each
    const int m   = blk*32 + row;    // global row
    const int b   = m >> 4;
    const int pos = m & 15, hb = pos>>2, wb = pos&3;
    float v[16];
#pragma unroll
    for (int h8 = 0; h8 < 2; h8++){
      const int c0 = kq*16 + h8*8;
      const int c = c0>>6, hr = (c0>>3)&7;
      const float* sp = &Fc[(((size_t)b*4+c)*32 + hb*8+hr)*32 + wb*8];
      float4 a = *(const float4*)sp;
      float4 bqq = *(const float4*)(sp+4);
      v[h8*8+0]=a.x; v[h8*8+1]=a.y; v[h8*8+2]=a.z; v[h8*8+3]=a.w;
      v[h8*8+4]=bqq.x; v[h8*8+5]=bqq.y; v[h8*8+6]=bqq.z; v[h8*8+7]=bqq.w;
    }
    float s = 0.f, q = 0.f;
#pragma unroll
    for (int e=0;e<16;e++){ s += v[e]; q += v[e]*v[e]; }
#pragma unroll
    for (int off=1; off<16; off<<=1){
      s += __shfl_xor(s, off);
      q += __shfl_xor(q, off);
    }
    const float mean = s*(1.f/256.f);
    const float var  = q*(1.f/256.f) - mean*mean;
    const float rs   = rsqrtf(var + 1e-6f);
    const float* mrow = &mods[(size_t)b*1536];
#pragma unroll
    for (int h8 = 0; h8 < 2; h8++){
      const int c0 = kq*16 + h8*8;
      uint2 o; u16 tmp[8];
#pragma unroll
      for (int e=0;e<8;e++){
        const float uv = (v[h8*8+e]-mean)*rs*(1.f+mrow[256+c0+e]) + mrow[c0+e];
        tmp[e] = f2bf(uv);
      }
      o.x = (u32)tmp[0] | ((u32)tmp[1]<<16);
      uint2 o2;
      o2.x = (u32)tmp[4] | ((u32)tmp[5]<<16);
      o2.y = (u32)tmp[6] | ((u32)tmp[7]<<16);
      o.y = (u32)tmp[2] | ((u32)tmp[3]<<16);
      const int slot = c0>>3;
      uint4 w4; w4.x=o.x; w4.y=o.y; w4.z=o2.x; w4.w=o2.y;
      *(uint4*)&u_lds[row*256 + 8*(slot ^ (row&7))] = w4;
    }
  }
  __syncthreads();

  // ---- P1: in_proj GEMM + conv/silu ----
  {
    f32x4 acc1[2][8];
#pragma unroll
    for (int i=0;i<2;i++)
#pragma unroll
      for (int j=0;j<8;j++) acc1[i][j] = (f32x4){0.f,0.f,0.f,0.f};

#pragma unroll 2
    for (int kt = 0; kt < 8; kt++){
      bf16x8 bw[8];
#pragma unroll
      for (int j=0;j<8;j++){
        const int col = wid*128 + j*16 + c16;
        bw[j] = *(const bf16x8*)&Win[(size_t)col*256 + kt*32 + g*8];
      }
      const int ks = kt*4 + g;
      bf16x8 au[2];
#pragma unroll
      for (int i=0;i<2;i++){
        const int row = i*16 + c16;
        au[i] = *(const bf16x8*)&u_lds[row*256 + 8*(ks ^ (row&7))];
      }
#pragma unroll
      for (int i=0;i<2;i++)
#pragma unroll
        for (int j=0;j<8;j++)
          acc1[i][j] = __builtin_amdgcn_mfma_f32_16x16x32_bf16(au[i], bw[j], acc1[i][j], 0,0,0);
    }

    if (wid < 4){
      // x-half: conv4 + silu -> xq_lds (swizzled)
#pragma unroll
      for (int j=0;j<8;j++){
        const int n = wid*128 + j*16 + c16;
        const float4 cwv = *(const float4*)&cw[n*4];
        const float cb0 = cb[n];
        const int sw_base = 8*((n>>3) /* ^ row&7 applied per row */);
#pragma unroll
        for (int i=0;i<2;i++){
          const float v0=acc1[i][j][0], v1=acc1[i][j][1], v2=acc1[i][j][2], v3=acc1[i][j][3];
          float p1 = __shfl(v1, (lane+48)&63);
          float p2 = __shfl(v2, (lane+48)&63);
          float p3 = __shfl(v3, (lane+48)&63);
          if (g==0){ p1=0.f; p2=0.f; p3=0.f; }
          float o0 = cb0 + cwv.w*v0 + cwv.z*p3 + cwv.y*p2 + cwv.x*p1;
          float o1 = cb0 + cwv.w*v1 + cwv.z*v0 + cwv.y*p3 + cwv.x*p2;
          float o2 = cb0 + cwv.w*v2 + cwv.z*v1 + cwv.y*v0 + cwv.x*p3;
          float o3 = cb0 + cwv.w*v3 + cwv.z*v2 + cwv.y*v1 + cwv.x*v0;
          o0 *= sigf(o0); o1 *= sigf(o1); o2 *= sigf(o2); o3 *= sigf(o3);
          const int r0 = i*16 + g*4;
          u16 ov[4] = { f2bf(o0), f2bf(o1), f2bf(o2), f2bf(o3) };
#pragma unroll
          for (int r=0;r<4;r++){
            const int row = r0 + r;
            xq_lds[row*512 + 8*((n>>3) ^ (row&7)) + (n&7)] = ov[r];
          }
          (void)sw_base;
        }
      }
    } else {
      // z-half: silu(z) -> zs_lds (linear)
#pragma unroll
      for (int j=0;j<8;j++){
        const int nz = (wid-4)*128 + j*16 + c16;
#pragma unroll
        for (int i=0;i<2;i++){
#pragma unroll
          for (int r=0;r<4;r++){
            const int row = i*16 + g*4 + r;
            const float z = acc1[i][j][r];
            zs_lds[row*512 + nz] = f2bf(z*sigf(z));
          }
        }
      }
    }
  }
  __syncthreads();

  // ---- P2: x_proj GEMM -> delta_lds, bc_lds ----
  {
    f32x4 acc2[5][2];
#pragma unroll
    for (int j=0;j<5;j++)
#pragma unroll
      for (int i=0;i<2;i++) acc2[j][i] = (f32x4){0.f,0.f,0.f,0.f};

#pragma unroll 2
    for (int kt = 0; kt < 16; kt++){
      bf16x8 bw[5];
#pragma unroll
      for (int j=0;j<4;j++){
        const int col = (wid + j*8)*16 + c16;
        bw[j] = *(const bf16x8*)&Wall[(size_t)col*512 + kt*32 + g*8];
      }
      if (wid < 2){
        const int col = (wid + 32)*16 + c16;
        bw[4] = *(const bf16x8*)&Wall[(size_t)col*512 + kt*32 + g*8];
      }
      const int ks = kt*4 + g;
      bf16x8 au[2];
#pragma unroll
      for (int i=0;i<2;i++){
        const int row = i*16 + c16;
        au[i] = *(const bf16x8*)&xq_lds[row*512 + 8*(ks ^ (row&7))];
      }
#pragma unroll
      for (int j=0;j<4;j++)
#pragma unroll
        for (int i=0;i<2;i++)
          acc2[j][i] = __builtin_amdgcn_mfma_f32_16x16x32_bf16(au[i], bw[j], acc2[j][i], 0,0,0);
      if (wid < 2){
#pragma unroll
        for (int i=0;i<2;i++)
          acc2[4][i] = __builtin_amdgcn_mfma_f32_16x16x32_bf16(au[i], bw[4], acc2[4][i], 0,0,0);
      }
    }
    // epilogue: delta (softplus) / BC
#pragma unroll
    for (int j=0;j<4;j++){
      const int n = (wid + j*8)*16 + c16;
      const float bv = dtb[n];
#pragma unroll
      for (int i=0;i<2;i++)
#pragma unroll
        for (int r=0;r<4;r++){
          const int row = i*16 + g*4 + r;
          const float dt = acc2[j][i][r] + bv;
          const float del = (dt > 20.f) ? dt : log1pf(__expf(dt));
          delta_lds[row*512 + n] = f2bf(del);
        }
    }
    if (wid < 2){
      const int n = (wid + 32)*16 + c16 - 512;   // 0..31
#pragma unroll
      for (int i=0;i<2;i++)
#pragma unroll
        for (int r=0;r<4;r++){
          const int row = i*16 + g*4 + r;
          bc_lds[row*32 + n] = acc2[4][i][r];
        }
    }
  }
  __syncthreads();

  // ---- P3: scan (thread = channel d, both batches) ----
  {
    const int d = tid;
    float An2[16];
#pragma unroll
    for (int n=0;n<16;n++) An2[n] = -__expf(A_log[d*16+n]) * 1.44269504f;
    const float Dv = Dskip[d];
    const int dsw_hi = d>>3, dlo = d&7;
#pragma unroll
    for (int i=0;i<2;i++){
      float h[16];
#pragma unroll
      for (int n=0;n<16;n++) h[n] = 0.f;
      u16* yp = Yout + (size_t)(blk*32 + i*16)*512 + d;
#pragma unroll
      for (int l=0;l<16;l++){
        const int row = i*16 + l;
        const float dl = bf2f(delta_lds[row*512 + d]);
        const float xl = bf2f(xq_lds[row*512 + 8*(dsw_hi ^ (row&7)) + dlo]);
        const float dx = dl*xl;
        float yv = Dv*xl;
        const float* bcp = &bc_lds[row*32];
#pragma unroll
        for (int n=0;n<16;n++){
          const float dA = EXP2F(dl*An2[n]);
          h[n] = fmaf(dA, h[n], bcp[n]*dx);
          yv = fmaf(h[n], bcp[16+n], yv);
        }
        const float zl = bf2f(zs_lds[row*512 + d]);
        yp[(size_t)l*512] = f2bf(yv*zl);
      }
    }
  }
}

// ---------------------------------------------------------------------------
// TAIL (unchanged from R7): out_proj + residual + LN + MLP + residual + unshuffle
// ---------------------------------------------------------------------------
__global__ __launch_bounds__(512) void tail_fused(
    const u16* __restrict__ Y, const u16* __restrict__ Wo,
    const u16* __restrict__ W1, const u16* __restrict__ W2,
    const float* __restrict__ Fc, const float* __restrict__ mods,
    const float* __restrict__ b1v, const float* __restrict__ b2v,
    float* __restrict__ out)
{
  __shared__ u16 Albuf[2][32*64];
  __shared__ u16 Wbuf[2][256*64];
  __shared__ u16 u2l[32*256];
  __shared__ u16 hm[32*256];
  __shared__ float redS[32][4], redQ[32][4];
  const int tid = threadIdx.x;
  const int lane = tid & 63, wid = tid >> 6;
  const int wr = wid >> 2, wc = wid & 3;
  const int m0 = blockIdx.x * 32;
  const int ln8 = lane>>3, lk = lane&7;
  const int g = lane>>4, c16 = lane&15;

  f32x4 acc[4];
#pragma unroll
  for (int j=0;j<4;j++) acc[j] = (f32x4){0.f,0.f,0.f,0.f};

  auto STAGE_A = [&](int buf, int k0){
    if (wid < 4){
      const int row = wid*8 + ln8;
      const int ks = lk ^ (row&7);
      gload16(Y + (size_t)(m0+row)*512 + k0 + 8*ks, &Albuf[buf][wid*512]);
    }
#pragma unroll
    for (int j=0;j<4;j++){
      const int c = j*8 + wid;
      const int row = c*8 + ln8;
      const int ks = lk ^ (row&7);
      gload16(Wo + (size_t)row*512 + k0 + 8*ks, &Wbuf[buf][c*512]);
    }
  };
  auto STAGE_W = [&](const u16* Wp, int buf, int k0){
#pragma unroll
    for (int j=0;j<4;j++){
      const int c = j*8 + wid;
      const int row = c*8 + ln8;
      const int ks = lk ^ (row&7);
      gload16(Wp + (size_t)row*256 + k0 + 8*ks, &Wbuf[buf][c*512]);
    }
  };
  auto COMPUTE_A = [&](int buf){
#pragma unroll
    for (int kk=0;kk<2;kk++){
      const int ks = kk*4 + g;
      const int row = wr*16 + c16;
      bf16x8 af = *(const bf16x8*)&Albuf[buf][row*64 + 8*(ks^(row&7))];
#pragma unroll
      for (int j=0;j<4;j++){
        const int col = wc*64 + j*16 + c16;
        bf16x8 bf = *(const bf16x8*)&Wbuf[buf][col*64 + 8*(ks^(col&7))];
        acc[j] = __builtin_amdgcn_mfma_f32_16x16x32_bf16(af, bf, acc[j], 0,0,0);
      }
    }
  };
  auto COMPUTE_L = [&](const u16* Am, int buf, int t){
#pragma unroll
    for (int kk=0;kk<2;kk++){
      const int ks = kk*4 + g;
      const int row = wr*16 + c16;
      bf16x8 af = *(const bf16x8*)&Am[row*256 + t*64 + 8*(ks^(row&7))];
#pragma unroll
      for (int j=0;j<4;j++){
        const int col = wc*64 + j*16 + c16;
        bf16x8 bf = *(const bf16x8*)&Wbuf[buf][col*64 + 8*(ks^(col&7))];
        acc[j] = __builtin_amdgcn_mfma_f32_16x16x32_bf16(af, bf, acc[j], 0,0,0);
      }
    }
  };

  // phase A: out_proj (K=512)
  STAGE_A(0,0);
  int cur = 0;
  for (int t=0;t<7;++t){
    STAGE_A(cur^1, (t+1)*64);
    if (wid<4) asm volatile("s_waitcnt vmcnt(5)" ::: "memory");
    else       asm volatile("s_waitcnt vmcnt(4)" ::: "memory");
    __builtin_amdgcn_s_barrier();
    COMPUTE_A(cur);
    asm volatile("s_waitcnt lgkmcnt(0)" ::: "memory");
    __builtin_amdgcn_s_barrier();
    cur ^= 1;
  }
  asm volatile("s_waitcnt vmcnt(0)" ::: "memory");
  __builtin_amdgcn_s_barrier();
  COMPUTE_A(cur);

  float xv[4][4];
  float s[4] = {0.f,0.f,0.f,0.f}, q[4] = {0.f,0.f,0.f,0.f};
#pragma unroll
  for (int j=0;j<4;j++){
    const int n = wc*64 + j*16 + c16;
#pragma unroll
    for (int r=0;r<4;r++){
      const int ml = wr*16 + g*4 + r;
      const int m = m0 + ml, b = m>>4;
      const int pos = m&15, c = n>>6, hr = (n>>3)&7, wrr = n&7;
      const int hh = (pos>>2)*8+hr, ww = (pos&3)*8+wrr;
      const float x0v = Fc[(((size_t)b*4+c)*32+hh)*32+ww];
      const float v = x0v + mods[(size_t)b*1536+512+n]*acc[j][r];
      xv[j][r] = v;
      s[r] += v; q[r] += v*v;
    }
  }
#pragma unroll
  for (int off=1; off<16; off<<=1){
#pragma unroll
    for (int r=0;r<4;r++){
      s[r] += __shfl_xor(s[r], off);
      q[r] += __shfl_xor(q[r], off);
    }
  }
  if (c16==0){
#pragma unroll
    for (int r=0;r<4;r++){
      redS[wr*16+g*4+r][wc] = s[r];
      redQ[wr*16+g*4+r][wc] = q[r];
    }
  }
  __syncthreads();
  float mean[4], rs[4];
#pragma unroll
  for (int r=0;r<4;r++){
    const int ml = wr*16 + g*4 + r;
    const float S = redS[ml][0]+redS[ml][1]+redS[ml][2]+redS[ml][3];
    const float Q = redQ[ml][0]+redQ[ml][1]+redQ[ml][2]+redQ[ml][3];
    mean[r] = S*(1.f/256.f);
    const float var = Q*(1.f/256.f) - mean[r]*mean[r];
    rs[r] = rsqrtf(var + 1e-6f);
  }
#pragma unroll
  for (int j=0;j<4;j++){
    const int n = wc*64 + j*16 + c16;
#pragma unroll
    for (int r=0;r<4;r++){
      const int ml = wr*16 + g*4 + r;
      const int m = m0 + ml, b = m>>4;
      const float u2v = (xv[j][r]-mean[r])*rs[r]*(1.f+mods[(size_t)b*1536+1024+n])
                        + mods[(size_t)b*1536+768+n];
      const int slot = j*2 + (c16>>3);
      u2l[ml*256 + wc*64 + 8*(slot ^ (ml&7)) + (c16&7)] = f2bf(u2v);
    }
  }
#pragma unroll
  for (int j=0;j<4;j++) acc[j] = (f32x4){0.f,0.f,0.f,0.f};
  __syncthreads();

  // phase B: fc1
  STAGE_W(W1, 0, 0);
  cur = 0;
  for (int t=0;t<3;++t){
    STAGE_W(W1, cur^1, (t+1)*64);
    asm volatile("s_waitcnt vmcnt(4)" ::: "memory");
    __builtin_amdgcn_s_barrier();
    COMPUTE_L(u2l, cur, t);
    asm volatile("s_waitcnt lgkmcnt(0)" ::: "memory");
    __builtin_amdgcn_s_barrier();
    cur ^= 1;
  }
  asm volatile("s_waitcnt vmcnt(0)" ::: "memory");
  __builtin_amdgcn_s_barrier();
  COMPUTE_L(u2l, cur, 3);

#pragma unroll
  for (int j=0;j<4;j++){
    const int n = wc*64 + j*16 + c16;
    const float bv = b1v[n];
#pragma unroll
    for (int r=0;r<4;r++){
      const int ml = wr*16 + g*4 + r;
      const float h = geluf(acc[j][r] + bv);
      const int slot = j*2 + (c16>>3);
      hm[ml*256 + wc*64 + 8*(slot ^ (ml&7)) + (c16&7)] = f2bf(h);
    }
  }
#pragma unroll
  for (int j=0;j<4;j++) acc[j] = (f32x4){0.f,0.f,0.f,0.f};
  __syncthreads();

  // phase C: fc2
  STAGE_W(W2, 0, 0);
  cur = 0;
  for (int t=0;t<3;++t){
    STAGE_W(W2, cur^1, (t+1)*64);
    asm volatile("s_waitcnt vmcnt(4)" ::: "memory");
    __builtin_amdgcn_s_barrier();
    COMPUTE_L(hm, cur, t);
    asm volatile("s_waitcnt lgkmcnt(0)" ::: "memory");
    __builtin_amdgcn_s_barrier();
    cur ^= 1;
  }
  asm volatile("s_waitcnt vmcnt(0)" ::: "memory");
  __builtin_amdgcn_s_barrier();
  COMPUTE_L(hm, cur, 3);

#pragma unroll
  for (int j=0;j<4;j++){
    const int n = wc*64 + j*16 + c16;
    const float bv = b2v[n];
#pragma unroll
    for (int r=0;r<4;r++){
      const int m = m0 + wr*16 + g*4 + r, b = m>>4;
      const float v = xv[j][r] + mods[(size_t)b*1536+1280+n]*(acc[j][r] + bv);
      const int pos = m&15, c = n>>6, hr=(n>>3)&7, wrr=n&7;
      const int hh = (pos>>2)*8+hr, ww = (pos&3)*8+wrr;
      out[(((size_t)b*4+c)*32+hh)*32+ww] = v;
    }
  }
}

// Setup: fp32->bf16 of F_clip + 6 weights (blocks 0..1559), plus the combined
// x_proj/dt_proj weight Wall (544x512, blocks 1560..2647)
__global__ __launch_bounds__(256) void setup_bf16(
    const float* __restrict__ clip, const float* __restrict__ fsw,
    const float* __restrict__ inp,  const float* __restrict__ xp,
    const float* __restrict__ outp, const float* __restrict__ f1,
    const float* __restrict__ f2,   const float* __restrict__ dtw,
    u16* __restrict__ dst, u16* __restrict__ wall)
{
  const int bid = blockIdx.x;
  if (bid < 1560){
    const int q = bid*256 + threadIdx.x;
    const float* s; int off;
    if      (q < 65536)  { s = clip; off = q*4; }
    else if (q < 262144) { s = fsw;  off = (q-65536)*4; }
    else if (q < 327680) { s = inp;  off = (q-262144)*4; }
    else if (q < 333824) { s = xp;   off = (q-327680)*4; }
    else if (q < 366592) { s = outp; off = (q-333824)*4; }
    else if (q < 382976) { s = f1;   off = (q-366592)*4; }
    else                 { s = f2;   off = (q-382976)*4; }
    float4 v = *(const float4*)&s[off];
    uint2 o;
    o.x = (u32)f2bf(v.x) | ((u32)f2bf(v.y)<<16);
    o.y = (u32)f2bf(v.z) | ((u32)f2bf(v.w)<<16);
    *(uint2*)&dst[(size_t)q*4] = o;
  } else {
    const int t = bid - 1560;              // 0..1087
    const int n = t >> 1;                  // 0..543
    const int k = (t & 1)*256 + threadIdx.x;
    float v;
    if (n < 512){
      v = 0.f;
#pragma unroll
      for (int r=0;r<16;r++) v = fmaf(dtw[n*16+r], xp[r*512+k], v);
    } else {
      v = xp[(size_t)(16 + n-512)*512 + k];
    }
    wall[(size_t)n*512+k] = f2bf(v);
  }
}

extern "C" void kernel_launch(void* const* d_in, const int* in_sizes, int n_in,
                              void* d_out, int out_size, void* d_ws, size_t ws_size,
                              hipStream_t stream)
{
  const float* F_clip    = (const float*)d_in[0];
  const float* F_content = (const float*)d_in[1];
  const float* fs_b      = (const float*)d_in[3];
  const float* conv_w    = (const float*)d_in[5];
  const float* conv_b    = (const float*)d_in[6];
  const float* x_proj_w  = (const float*)d_in[7];
  const float* dt_proj_w = (const float*)d_in[8];
  const float* dt_proj_b = (const float*)d_in[9];
  const float* A_log     = (const float*)d_in[10];
  const float* D_skip    = (const float*)d_in[11];
  const float* fc1_b     = (const float*)d_in[14];
  const float* fc2_b     = (const float*)d_in[16];
  float* out = (float*)d_out;

  float* ws = (float*)d_ws;
  float* w_mods = ws;                      // 786432 f
  u16* y_bf    = (u16*)(w_mods + 786432);  // 4194304 h  (8192 x 512)
  u16* wall_bf = y_bf + 4194304;           // 278528 h   (544 x 512)
  u16* wt_bf   = wall_bf + 278528;         // 1597440 h  => ~15 MB total

  u16* clip_bf = wt_bf;
  u16* fsw_bf  = wt_bf + 262144;
  u16* inp_bf  = wt_bf + 1048576;
  u16* outp_bf = wt_bf + 1335296;
  u16* fc1_bf  = wt_bf + 1466368;
  u16* fc2_bf  = wt_bf + 1531904;

  // K0: fp32 -> bf16 conversions + combined x_proj/dt_proj weight
  setup_bf16<<<2648,256,0,stream>>>(F_clip, (const float*)d_in[2],
      (const float*)d_in[4], x_proj_w, (const float*)d_in[12],
      (const float*)d_in[13], (const float*)d_in[15], dt_proj_w,
      wt_bf, wall_bf);
  // K1: mods = F_clip @ fs_w.T + fs_b           (512 x 1536, K=512)
  gemm_mods<<<dim3(24,8),256,0,stream>>>(clip_bf, fsw_bf, fs_b, w_mods);
  // K2: the whole mamba middle, one block per 2 batches
  mamba_core<<<256,512,0,stream>>>(F_content, w_mods, inp_bf, wall_bf,
      conv_w, conv_b, dt_proj_b, A_log, D_skip, y_bf);
  // K3: out_proj + residual + LN + MLP + residual + unshuffle -> out
  tail_fused<<<256,512,0,stream>>>(y_bf, outp_bf, fc1_bf, fc2_bf,
      F_content, w_mods, fc1_b, fc2_b, out);
}